// Round 1
// baseline (404.356 us; speedup 1.0000x reference)
//
#include <hip/hip_runtime.h>
#include <hip/hip_bf16.h>

#define B_   2
#define S_   2048
#define DM   2048
#define NH   32
#define NKV  8
#define HD   64
#define MROWS 4096   // B_*S_
#define NQKV  3072   // (NH+2*NKV)*HD

typedef __attribute__((ext_vector_type(8))) short bf16x8;
typedef __attribute__((ext_vector_type(4))) float f32x4;

__device__ __forceinline__ unsigned short f2b(float f) {
  __hip_bfloat16 h = __float2bfloat16(f);
  return *reinterpret_cast<unsigned short*>(&h);
}

__device__ __forceinline__ void gload16(const void* g, void* l) {
  __builtin_amdgcn_global_load_lds((__attribute__((address_space(1))) void*)g,
                                   (__attribute__((address_space(3))) void*)l,
                                   16, 0, 0);
}

// ---------------- fp32 -> bf16 convert ----------------
__global__ __launch_bounds__(256) void f2bf_kernel(const float* __restrict__ in,
                                                   unsigned short* __restrict__ out, int n4) {
  int i = blockIdx.x * 256 + threadIdx.x;
  if (i < n4) {
    float4 v = reinterpret_cast<const float4*>(in)[i];
    ushort4 o;
    o.x = f2b(v.x); o.y = f2b(v.y); o.z = f2b(v.z); o.w = f2b(v.w);
    reinterpret_cast<ushort4*>(out)[i] = o;
  }
}

// ---------------- concat wq|wk|wv -> bf16 [3072][2048] ----------------
__global__ __launch_bounds__(256) void wcat_kernel(const float* __restrict__ wq,
                                                   const float* __restrict__ wk,
                                                   const float* __restrict__ wv,
                                                   unsigned short* __restrict__ out) {
  int i = blockIdx.x * 256 + threadIdx.x;        // chunk of 4 elems; total 1572864
  int e = i * 4;
  int row = e >> 11;
  int col = e & 2047;
  const float* src;
  if (row < 2048)      src = wq + (size_t)row * 2048 + col;
  else if (row < 2560) src = wk + (size_t)(row - 2048) * 2048 + col;
  else                 src = wv + (size_t)(row - 2560) * 2048 + col;
  float4 v = *reinterpret_cast<const float4*>(src);
  ushort4 o;
  o.x = f2b(v.x); o.y = f2b(v.y); o.z = f2b(v.z); o.w = f2b(v.w);
  reinterpret_cast<ushort4*>(out)[i] = o;
}

// ---------------- GEMM C[M,N] = A[M,K] * B[N,K]^T  (bf16 in, fp32 out) ----------------
// m97 structure: 128x128 tile, BK=64, 4 waves, global_load_lds width 16.
__global__ __launch_bounds__(256) void gemm_bt(const unsigned short* __restrict__ A,
                                               const unsigned short* __restrict__ Bm,
                                               float* __restrict__ C,
                                               int M, int N, int K) {
  __shared__ unsigned short Ab[128 * 64];
  __shared__ unsigned short Bb[128 * 64];
  const int tid = threadIdx.x;
  const int wave = tid >> 6, lane = tid & 63;
  const int wr = wave >> 1, wc = wave & 1;
  const int rowbase = blockIdx.y * 128;
  const int colbase = blockIdx.x * 128;

  f32x4 acc[4][4];
#pragma unroll
  for (int a = 0; a < 4; a++)
#pragma unroll
    for (int b2 = 0; b2 < 4; b2++) acc[a][b2] = (f32x4){0.f, 0.f, 0.f, 0.f};

  const int r8 = lane >> 3;
  const int c8 = (lane & 7) * 8;
  const unsigned short* Ag = A + (size_t)rowbase * K;
  const unsigned short* Bg = Bm + (size_t)colbase * K;

  for (int k0 = 0; k0 < K; k0 += 64) {
#pragma unroll
    for (int c = 0; c < 4; c++) {
      int rowg = (wave * 4 + c) * 8;
      gload16(Ag + (size_t)(rowg + r8) * K + k0 + c8, &Ab[rowg * 64]);
      gload16(Bg + (size_t)(rowg + r8) * K + k0 + c8, &Bb[rowg * 64]);
    }
    __syncthreads();
#pragma unroll
    for (int kk = 0; kk < 64; kk += 32) {
      bf16x8 af[4], bfr[4];
#pragma unroll
      for (int mt = 0; mt < 4; mt++)
        af[mt] = *reinterpret_cast<const bf16x8*>(
            &Ab[(wr * 64 + mt * 16 + (lane & 15)) * 64 + kk + (lane >> 4) * 8]);
#pragma unroll
      for (int nt = 0; nt < 4; nt++)
        bfr[nt] = *reinterpret_cast<const bf16x8*>(
            &Bb[(wc * 64 + nt * 16 + (lane & 15)) * 64 + kk + (lane >> 4) * 8]);
#pragma unroll
      for (int mt = 0; mt < 4; mt++)
#pragma unroll
        for (int nt = 0; nt < 4; nt++)
          acc[mt][nt] = __builtin_amdgcn_mfma_f32_16x16x32_bf16(af[mt], bfr[nt], acc[mt][nt], 0, 0, 0);
    }
    __syncthreads();
  }

  const int orow = rowbase + wr * 64, ocol = colbase + wc * 64;
#pragma unroll
  for (int mt = 0; mt < 4; mt++)
#pragma unroll
    for (int nt = 0; nt < 4; nt++)
#pragma unroll
      for (int r = 0; r < 4; r++)
        C[(size_t)(orow + mt * 16 + (lane >> 4) * 4 + r) * N + ocol + nt * 16 + (lane & 15)] =
            acc[mt][nt][r];
}

// ---------------- RoPE + layout: qkv fp32 -> Q/K/V^T bf16 ----------------
__global__ __launch_bounds__(256) void rope_kernel(const float* __restrict__ qkv,
                                                   const float* __restrict__ cosg,
                                                   const float* __restrict__ sing,
                                                   unsigned short* __restrict__ Qb,
                                                   unsigned short* __restrict__ Kb,
                                                   unsigned short* __restrict__ Vtb) {
  const int row = blockIdx.x;              // b*S + s
  const int b = row >> 11, s = row & 2047;
  __shared__ float cs[32], sn[32];
  if (threadIdx.x < 32) {
    cs[threadIdx.x] = cosg[s * 32 + threadIdx.x];
    sn[threadIdx.x] = sing[s * 32 + threadIdx.x];
  }
  __syncthreads();
  const float* qr = qkv + (size_t)row * NQKV;
  const int t = threadIdx.x;

  // Q: 32 heads x 32 pairs (d, d+32); cos2[d] = cos[d>>1]
  for (int pid = t; pid < 1024; pid += 256) {
    const int h = pid >> 5, i = pid & 31, i2 = i >> 1;
    float qa = qr[h * 64 + i], qb2 = qr[h * 64 + i + 32];
    size_t base = ((size_t)(b * NH + h) * S_ + s) * HD;
    Qb[base + i]      = f2b(qa * cs[i2] - qb2 * sn[i2]);
    Qb[base + i + 32] = f2b(qb2 * cs[16 + i2] + qa * sn[16 + i2]);
  }
  // K: 8 heads x 32 pairs
  {
    const int h = t >> 5, i = t & 31, i2 = i >> 1;
    float ka = qr[2048 + h * 64 + i], kb2 = qr[2048 + h * 64 + i + 32];
    size_t base = ((size_t)(b * NKV + h) * S_ + s) * HD;
    Kb[base + i]      = f2b(ka * cs[i2] - kb2 * sn[i2]);
    Kb[base + i + 32] = f2b(kb2 * cs[16 + i2] + ka * sn[16 + i2]);
  }
  // V -> transposed [B][Hkv][64][S]
  for (int j = t; j < 512; j += 256) {
    const int h = j >> 6, d = j & 63;
    Vtb[((size_t)(b * NKV + h) * HD + d) * S_ + s] = f2b(qr[2560 + j]);
  }
}

// ---------------- Flash attention: Q tile 64, KV tiles 64, 4 waves ----------------
__global__ __launch_bounds__(256) void attn_kernel(const unsigned short* __restrict__ Q,
                                                   const unsigned short* __restrict__ Kg,
                                                   const unsigned short* __restrict__ Vt,
                                                   unsigned short* __restrict__ AO) {
  const int qt = blockIdx.x, h = blockIdx.y, b = blockIdx.z;
  const int hk = h >> 2;                  // repeat_interleave: head h -> kv head h/4
  const int q0 = qt * 64;
  __shared__ unsigned short Klds[64 * 72];   // pad stride 72 (144B = 9x16B, 2-way only)
  __shared__ unsigned short Vlds[64 * 72];
  __shared__ unsigned short Plds[4][16 * 72];
  const int tid = threadIdx.x, wave = tid >> 6, lane = tid & 63;
  const int arow = lane & 15, kg = (lane >> 4) * 8;

  const unsigned short* Qbase = Q + ((size_t)(b * NH + h) * S_ + q0 + wave * 16) * HD;
  bf16x8 qf0 = *reinterpret_cast<const bf16x8*>(&Qbase[(size_t)arow * HD + kg]);
  bf16x8 qf1 = *reinterpret_cast<const bf16x8*>(&Qbase[(size_t)arow * HD + 32 + kg]);
  const unsigned short* Kbase = Kg + (size_t)(b * NKV + hk) * S_ * HD;
  const unsigned short* Vbase = Vt + (size_t)(b * NKV + hk) * HD * S_;

  float mreg[4] = {-INFINITY, -INFINITY, -INFINITY, -INFINITY};
  float lreg[4] = {0.f, 0.f, 0.f, 0.f};
  f32x4 o[4];
#pragma unroll
  for (int nt = 0; nt < 4; nt++) o[nt] = (f32x4){0.f, 0.f, 0.f, 0.f};

  for (int j0 = 0; j0 <= q0; j0 += 64) {
    __syncthreads();
    // stage K [64][64] and V^T [64][64]
    for (int c = tid; c < 512; c += 256) {
      int row = c >> 3, co = (c & 7) * 8;
      *reinterpret_cast<bf16x8*>(&Klds[row * 72 + co]) =
          *reinterpret_cast<const bf16x8*>(&Kbase[(size_t)(j0 + row) * HD + co]);
      *reinterpret_cast<bf16x8*>(&Vlds[row * 72 + co]) =
          *reinterpret_cast<const bf16x8*>(&Vbase[(size_t)row * S_ + j0 + co]);
    }
    __syncthreads();

    // S = Q K^T (16x64 per wave)
    f32x4 sc[4];
#pragma unroll
    for (int nt = 0; nt < 4; nt++) {
      bf16x8 kf0 = *reinterpret_cast<const bf16x8*>(&Klds[(nt * 16 + arow) * 72 + kg]);
      bf16x8 kf1 = *reinterpret_cast<const bf16x8*>(&Klds[(nt * 16 + arow) * 72 + 32 + kg]);
      f32x4 z = (f32x4){0.f, 0.f, 0.f, 0.f};
      z = __builtin_amdgcn_mfma_f32_16x16x32_bf16(qf0, kf0, z, 0, 0, 0);
      sc[nt] = __builtin_amdgcn_mfma_f32_16x16x32_bf16(qf1, kf1, z, 0, 0, 0);
    }

    const int rbase = q0 + wave * 16 + (lane >> 4) * 4;
    const bool diag = (j0 == q0);
#pragma unroll
    for (int nt = 0; nt < 4; nt++)
#pragma unroll
      for (int r = 0; r < 4; r++) {
        float s = sc[nt][r] * 0.125f;
        if (diag && (j0 + nt * 16 + arow) > (rbase + r)) s = -INFINITY;
        sc[nt][r] = s;
      }

    // online softmax (rows spread over 16 lanes)
    float corr[4];
#pragma unroll
    for (int r = 0; r < 4; r++) {
      float rm = fmaxf(fmaxf(sc[0][r], sc[1][r]), fmaxf(sc[2][r], sc[3][r]));
#pragma unroll
      for (int msk = 1; msk < 16; msk <<= 1) rm = fmaxf(rm, __shfl_xor(rm, msk, 64));
      float mn = fmaxf(mreg[r], rm);
      corr[r] = __expf(mreg[r] - mn);
      mreg[r] = mn;
    }
    float rsum[4] = {0.f, 0.f, 0.f, 0.f};
#pragma unroll
    for (int nt = 0; nt < 4; nt++)
#pragma unroll
      for (int r = 0; r < 4; r++) {
        float p = __expf(sc[nt][r] - mreg[r]);
        sc[nt][r] = p;
        rsum[r] += p;
      }
#pragma unroll
    for (int r = 0; r < 4; r++) {
#pragma unroll
      for (int msk = 1; msk < 16; msk <<= 1) rsum[r] += __shfl_xor(rsum[r], msk, 64);
      lreg[r] = lreg[r] * corr[r] + rsum[r];
    }
#pragma unroll
    for (int nt = 0; nt < 4; nt++)
#pragma unroll
      for (int r = 0; r < 4; r++) o[nt][r] *= corr[r];

    // P -> LDS (C-layout write, A-layout read)
    unsigned short* P = &Plds[wave][0];
#pragma unroll
    for (int nt = 0; nt < 4; nt++)
#pragma unroll
      for (int r = 0; r < 4; r++)
        P[((lane >> 4) * 4 + r) * 72 + nt * 16 + arow] = f2b(sc[nt][r]);

    // O += P V
#pragma unroll
    for (int ks = 0; ks < 2; ks++) {
      bf16x8 pf = *reinterpret_cast<const bf16x8*>(&P[arow * 72 + ks * 32 + kg]);
#pragma unroll
      for (int nt = 0; nt < 4; nt++) {
        bf16x8 vf = *reinterpret_cast<const bf16x8*>(&Vlds[(nt * 16 + arow) * 72 + ks * 32 + kg]);
        o[nt] = __builtin_amdgcn_mfma_f32_16x16x32_bf16(pf, vf, o[nt], 0, 0, 0);
      }
    }
  }

  // epilogue: normalize, write AO [B][S][H][64] bf16
#pragma unroll
  for (int r = 0; r < 4; r++) {
    float inv = 1.0f / lreg[r];
    int srow = q0 + wave * 16 + (lane >> 4) * 4 + r;
    size_t base = ((size_t)(b * S_ + srow) * NH + h) * HD;
#pragma unroll
    for (int nt = 0; nt < 4; nt++)
      AO[base + nt * 16 + arow] = f2b(o[nt][r] * inv);
  }
}

extern "C" void kernel_launch(void* const* d_in, const int* in_sizes, int n_in,
                              void* d_out, int out_size, void* d_ws, size_t ws_size,
                              hipStream_t stream) {
  (void)in_sizes; (void)n_in; (void)out_size; (void)ws_size;
  const float* x    = (const float*)d_in[0];
  const float* wq   = (const float*)d_in[1];
  const float* wk   = (const float*)d_in[2];
  const float* wv   = (const float*)d_in[3];
  const float* wo   = (const float*)d_in[4];
  const float* cosg = (const float*)d_in[5];
  const float* sing = (const float*)d_in[6];

  char* ws = (char*)d_ws;
  // layout (bytes):
  unsigned short* xb   = (unsigned short*)(ws);                 // 16,777,216  (also reused as AO)
  unsigned short* wcat = (unsigned short*)(ws + 16777216);      // 12,582,912
  unsigned short* wob  = (unsigned short*)(ws + 29360128);      //  8,388,608
  float*          qkv  = (float*)         (ws + 37748736);      // 50,331,648
  unsigned short* Qb   = (unsigned short*)(ws + 88080384);      // 16,777,216
  unsigned short* Kb   = (unsigned short*)(ws + 104857600);     //  4,194,304
  unsigned short* Vtb  = (unsigned short*)(ws + 109051904);     //  4,194,304
  unsigned short* AO   = xb;  // xb dead after gemm1; reuse     -> total 113,246,208 B

  f2bf_kernel<<<8192, 256, 0, stream>>>(x, xb, 2097152);          // x -> bf16
  wcat_kernel<<<6144, 256, 0, stream>>>(wq, wk, wv, wcat);        // wq|wk|wv -> bf16
  f2bf_kernel<<<4096, 256, 0, stream>>>(wo, wob, 1048576);        // wo -> bf16

  gemm_bt<<<dim3(NQKV / 128, MROWS / 128), 256, 0, stream>>>(xb, wcat, qkv, MROWS, NQKV, DM);

  rope_kernel<<<MROWS, 256, 0, stream>>>(qkv, cosg, sing, Qb, Kb, Vtb);

  attn_kernel<<<dim3(S_ / 64, NH, B_), 256, 0, stream>>>(Qb, Kb, Vtb, AO);

  gemm_bt<<<dim3(DM / 128, MROWS / 128), 256, 0, stream>>>(AO, wob, (float*)d_out, MROWS, DM, DM);
}

// Round 2
// 303.801 us; speedup vs baseline: 1.3310x; 1.3310x over previous
//
#include <hip/hip_runtime.h>
#include <hip/hip_bf16.h>

#define B_   2
#define S_   2048
#define DM   2048
#define NH   32
#define NKV  8
#define HD   64
#define MROWS 4096   // B_*S_
#define NQKV  3072   // (NH+2*NKV)*HD

typedef __attribute__((ext_vector_type(8))) short bf16x8;
typedef __attribute__((ext_vector_type(4))) float f32x4;
typedef __attribute__((ext_vector_type(16))) float f32x16;

__device__ __forceinline__ unsigned short f2b(float f) {
  __hip_bfloat16 h = __float2bfloat16(f);
  return *reinterpret_cast<unsigned short*>(&h);
}

__device__ __forceinline__ void gload16(const void* g, void* l) {
  __builtin_amdgcn_global_load_lds((__attribute__((address_space(1))) void*)g,
                                   (__attribute__((address_space(3))) void*)l,
                                   16, 0, 0);
}

__device__ __forceinline__ unsigned cvtpk(float lo, float hi) {
  unsigned r;
  asm("v_cvt_pk_bf16_f32 %0, %1, %2" : "=v"(r) : "v"(lo), "v"(hi));
  return r;
}

__device__ __forceinline__ void pl32swap(unsigned& a, unsigned& b) {
  asm volatile("v_permlane32_swap_b32 %0, %1" : "+v"(a), "+v"(b));
}

__device__ __forceinline__ bf16x8 mk8(unsigned w0, unsigned w1, unsigned w2, unsigned w3) {
  union { unsigned u[4]; bf16x8 v; } uu;
  uu.u[0] = w0; uu.u[1] = w1; uu.u[2] = w2; uu.u[3] = w3;
  return uu.v;
}

// ---------------- fp32 -> bf16 convert ----------------
__global__ __launch_bounds__(256) void f2bf_kernel(const float* __restrict__ in,
                                                   unsigned short* __restrict__ out, int n4) {
  int i = blockIdx.x * 256 + threadIdx.x;
  if (i < n4) {
    float4 v = reinterpret_cast<const float4*>(in)[i];
    ushort4 o;
    o.x = f2b(v.x); o.y = f2b(v.y); o.z = f2b(v.z); o.w = f2b(v.w);
    reinterpret_cast<ushort4*>(out)[i] = o;
  }
}

// ---------------- concat wq|wk|wv -> bf16 [3072][2048] ----------------
__global__ __launch_bounds__(256) void wcat_kernel(const float* __restrict__ wq,
                                                   const float* __restrict__ wk,
                                                   const float* __restrict__ wv,
                                                   unsigned short* __restrict__ out) {
  int i = blockIdx.x * 256 + threadIdx.x;
  int e = i * 4;
  int row = e >> 11;
  int col = e & 2047;
  const float* src;
  if (row < 2048)      src = wq + (size_t)row * 2048 + col;
  else if (row < 2560) src = wk + (size_t)(row - 2048) * 2048 + col;
  else                 src = wv + (size_t)(row - 2560) * 2048 + col;
  float4 v = *reinterpret_cast<const float4*>(src);
  ushort4 o;
  o.x = f2b(v.x); o.y = f2b(v.y); o.z = f2b(v.z); o.w = f2b(v.w);
  reinterpret_cast<ushort4*>(out)[i] = o;
}

// ---------------- GEMM C[M,N] = A[M,K] * B[N,K]^T  (bf16 in, fp32 out) ----------------
__global__ __launch_bounds__(256) void gemm_bt(const unsigned short* __restrict__ A,
                                               const unsigned short* __restrict__ Bm,
                                               float* __restrict__ C,
                                               int M, int N, int K) {
  __shared__ unsigned short Ab[128 * 64];
  __shared__ unsigned short Bb[128 * 64];
  const int tid = threadIdx.x;
  const int wave = tid >> 6, lane = tid & 63;
  const int wr = wave >> 1, wc = wave & 1;
  const int rowbase = blockIdx.y * 128;
  const int colbase = blockIdx.x * 128;

  f32x4 acc[4][4];
#pragma unroll
  for (int a = 0; a < 4; a++)
#pragma unroll
    for (int b2 = 0; b2 < 4; b2++) acc[a][b2] = (f32x4){0.f, 0.f, 0.f, 0.f};

  const int r8 = lane >> 3;
  const int c8 = (lane & 7) * 8;
  const unsigned short* Ag = A + (size_t)rowbase * K;
  const unsigned short* Bg = Bm + (size_t)colbase * K;

  for (int k0 = 0; k0 < K; k0 += 64) {
#pragma unroll
    for (int c = 0; c < 4; c++) {
      int rowg = (wave * 4 + c) * 8;
      gload16(Ag + (size_t)(rowg + r8) * K + k0 + c8, &Ab[rowg * 64]);
      gload16(Bg + (size_t)(rowg + r8) * K + k0 + c8, &Bb[rowg * 64]);
    }
    __syncthreads();
#pragma unroll
    for (int kk = 0; kk < 64; kk += 32) {
      bf16x8 af[4], bfr[4];
#pragma unroll
      for (int mt = 0; mt < 4; mt++)
        af[mt] = *reinterpret_cast<const bf16x8*>(
            &Ab[(wr * 64 + mt * 16 + (lane & 15)) * 64 + kk + (lane >> 4) * 8]);
#pragma unroll
      for (int nt = 0; nt < 4; nt++)
        bfr[nt] = *reinterpret_cast<const bf16x8*>(
            &Bb[(wc * 64 + nt * 16 + (lane & 15)) * 64 + kk + (lane >> 4) * 8]);
#pragma unroll
      for (int mt = 0; mt < 4; mt++)
#pragma unroll
        for (int nt = 0; nt < 4; nt++)
          acc[mt][nt] = __builtin_amdgcn_mfma_f32_16x16x32_bf16(af[mt], bfr[nt], acc[mt][nt], 0, 0, 0);
    }
    __syncthreads();
  }

  const int orow = rowbase + wr * 64, ocol = colbase + wc * 64;
#pragma unroll
  for (int mt = 0; mt < 4; mt++)
#pragma unroll
    for (int nt = 0; nt < 4; nt++)
#pragma unroll
      for (int r = 0; r < 4; r++)
        C[(size_t)(orow + mt * 16 + (lane >> 4) * 4 + r) * N + ocol + nt * 16 + (lane & 15)] =
            acc[mt][nt][r];
}

// ---------------- RoPE + layout: qkv fp32 -> Q/K/V^T bf16 ----------------
__global__ __launch_bounds__(256) void rope_kernel(const float* __restrict__ qkv,
                                                   const float* __restrict__ cosg,
                                                   const float* __restrict__ sing,
                                                   unsigned short* __restrict__ Qb,
                                                   unsigned short* __restrict__ Kb,
                                                   unsigned short* __restrict__ Vtb) {
  const int row = blockIdx.x;              // b*S + s
  const int b = row >> 11, s = row & 2047;
  __shared__ float cs[32], sn[32];
  if (threadIdx.x < 32) {
    cs[threadIdx.x] = cosg[s * 32 + threadIdx.x];
    sn[threadIdx.x] = sing[s * 32 + threadIdx.x];
  }
  __syncthreads();
  const float* qr = qkv + (size_t)row * NQKV;
  const int t = threadIdx.x;

  for (int pid = t; pid < 1024; pid += 256) {
    const int h = pid >> 5, i = pid & 31, i2 = i >> 1;
    float qa = qr[h * 64 + i], qb2 = qr[h * 64 + i + 32];
    size_t base = ((size_t)(b * NH + h) * S_ + s) * HD;
    Qb[base + i]      = f2b(qa * cs[i2] - qb2 * sn[i2]);
    Qb[base + i + 32] = f2b(qb2 * cs[16 + i2] + qa * sn[16 + i2]);
  }
  {
    const int h = t >> 5, i = t & 31, i2 = i >> 1;
    float ka = qr[2048 + h * 64 + i], kb2 = qr[2048 + h * 64 + i + 32];
    size_t base = ((size_t)(b * NKV + h) * S_ + s) * HD;
    Kb[base + i]      = f2b(ka * cs[i2] - kb2 * sn[i2]);
    Kb[base + i + 32] = f2b(kb2 * cs[16 + i2] + ka * sn[16 + i2]);
  }
  for (int j = t; j < 512; j += 256) {
    const int h = j >> 6, d = j & 63;
    Vtb[((size_t)(b * NKV + h) * HD + d) * S_ + s] = f2b(qr[2560 + j]);
  }
}

// ---------------- Flash attention: 4 waves x 32 q-rows, KV tiles 64, swapped QK ----------------
__device__ __forceinline__ void stage_kv(const unsigned short* __restrict__ Kbase,
                                         const unsigned short* __restrict__ Vbase,
                                         unsigned short* Kl, unsigned short* Vl,
                                         int j0, int wave, int lane) {
#pragma unroll
  for (int tt = 0; tt < 2; ++tt) {
    int slot = (wave * 2 + tt) * 64 + lane;
    int row = slot >> 3, blk = slot & 7;
    int sb = ((blk ^ (row & 7)) << 3);          // pre-swizzled global source (rule 21)
    gload16(Kbase + (size_t)(j0 + row) * HD + sb, Kl + (wave * 2 + tt) * 512);
    gload16(Vbase + (size_t)row * S_ + j0 + sb, Vl + (wave * 2 + tt) * 512);
  }
}

__global__ __launch_bounds__(256) void attn_kernel(const unsigned short* __restrict__ Q,
                                                   const unsigned short* __restrict__ Kg,
                                                   const unsigned short* __restrict__ Vt,
                                                   unsigned short* __restrict__ AO) {
  const int qbi = blockIdx.x, h = blockIdx.y, b = blockIdx.z;
  const int hk = h >> 2;
  const int qb = qbi * 128;
  __shared__ unsigned short lds_all[16384];   // [2 buf][K 4096] + [2 buf][V 4096]
  const int tid = threadIdx.x, wave = tid >> 6, lane = tid & 63;
  const int l31 = lane & 31, hi = lane >> 5;
  const int q0w = qb + wave * 32;
  const int qg = q0w + l31;

  const unsigned short* Qbase = Q + (size_t)(b * NH + h) * S_ * HD;
  const unsigned short* Kbase = Kg + (size_t)(b * NKV + hk) * S_ * HD;
  const unsigned short* Vbase = Vt + (size_t)(b * NKV + hk) * HD * S_;

  bf16x8 qf[4];
#pragma unroll
  for (int c = 0; c < 4; ++c)
    qf[c] = *reinterpret_cast<const bf16x8*>(Qbase + (size_t)qg * HD + c * 16 + hi * 8);

  f32x16 Oa0 = {}, Oa1 = {};
  float m_old = -INFINITY, lsum = 0.f;

  const int NT = (qb + 128) / 64;

  stage_kv(Kbase, Vbase, lds_all, lds_all + 8192, 0, wave, lane);
  __syncthreads();
  int cur = 0;

  for (int t = 0; t < NT; ++t) {
    const int j0 = t * 64;
    if (t + 1 < NT)
      stage_kv(Kbase, Vbase, lds_all + (cur ^ 1) * 4096, lds_all + 8192 + (cur ^ 1) * 4096,
               (t + 1) * 64, wave, lane);

    if (j0 < q0w + 32) {
      const char* Klc = (const char*)(lds_all + cur * 4096);
      const char* Vlc = (const char*)(lds_all + 8192 + cur * 4096);

      // S = K * Q  (scores transposed: lane owns q = qg, 32 k-values across regs)
      f32x16 s0 = {}, s1 = {};
#pragma unroll
      for (int c = 0; c < 4; ++c) {
        const int r0 = l31;
        bf16x8 kf = *(const bf16x8*)(Klc + r0 * 128 + ((((c << 1) + hi) ^ (r0 & 7)) << 4));
        s0 = __builtin_amdgcn_mfma_f32_32x32x16_bf16(kf, qf[c], s0, 0, 0, 0);
      }
#pragma unroll
      for (int c = 0; c < 4; ++c) {
        const int r1 = 32 + l31;
        bf16x8 kf = *(const bf16x8*)(Klc + r1 * 128 + ((((c << 1) + hi) ^ (r1 & 7)) << 4));
        s1 = __builtin_amdgcn_mfma_f32_32x32x16_bf16(kf, qf[c], s1, 0, 0, 0);
      }

      // scale + causal mask + row max (in-lane + one cross-half shfl)
      float mx = m_old;
      const bool need_mask = (j0 + 63 > q0w);
      const int kb0 = j0 + 4 * hi, kb1 = j0 + 32 + 4 * hi;
      if (need_mask) {
#pragma unroll
        for (int r = 0; r < 16; ++r) {
          const int ko = (r & 3) + 8 * (r >> 2);
          float v0 = s0[r] * 0.125f; if (kb0 + ko > qg) v0 = -INFINITY;
          s0[r] = v0; mx = fmaxf(mx, v0);
          float v1 = s1[r] * 0.125f; if (kb1 + ko > qg) v1 = -INFINITY;
          s1[r] = v1; mx = fmaxf(mx, v1);
        }
      } else {
#pragma unroll
        for (int r = 0; r < 16; ++r) {
          float v0 = s0[r] * 0.125f; s0[r] = v0; mx = fmaxf(mx, v0);
          float v1 = s1[r] * 0.125f; s1[r] = v1; mx = fmaxf(mx, v1);
        }
      }
      mx = fmaxf(mx, __shfl_xor(mx, 32, 64));
      const float corr = __expf(m_old - mx);
      m_old = mx;

      float rs = 0.f;
#pragma unroll
      for (int r = 0; r < 16; ++r) {
        float p0 = __expf(s0[r] - mx); s0[r] = p0; rs += p0;
        float p1 = __expf(s1[r] - mx); s1[r] = p1; rs += p1;
      }
      rs += __shfl_xor(rs, 32, 64);
      lsum = lsum * corr + rs;
#pragma unroll
      for (int r = 0; r < 16; ++r) { Oa0[r] *= corr; Oa1[r] *= corr; }

      // P -> bf16 B-fragments in-register (cvt_pk + permlane32_swap)
      unsigned a0 = cvtpk(s0[0], s0[1]),  b0 = cvtpk(s0[4], s0[5]);  pl32swap(a0, b0);
      unsigned a1 = cvtpk(s0[2], s0[3]),  b1 = cvtpk(s0[6], s0[7]);  pl32swap(a1, b1);
      bf16x8 pf00 = mk8(a0, a1, b0, b1);
      unsigned a2 = cvtpk(s0[8], s0[9]),  b2 = cvtpk(s0[12], s0[13]); pl32swap(a2, b2);
      unsigned a3 = cvtpk(s0[10], s0[11]), b3 = cvtpk(s0[14], s0[15]); pl32swap(a3, b3);
      bf16x8 pf01 = mk8(a2, a3, b2, b3);
      unsigned a4 = cvtpk(s1[0], s1[1]),  b4 = cvtpk(s1[4], s1[5]);  pl32swap(a4, b4);
      unsigned a5 = cvtpk(s1[2], s1[3]),  b5 = cvtpk(s1[6], s1[7]);  pl32swap(a5, b5);
      bf16x8 pf10 = mk8(a4, a5, b4, b5);
      unsigned a6 = cvtpk(s1[8], s1[9]),  b6 = cvtpk(s1[12], s1[13]); pl32swap(a6, b6);
      unsigned a7 = cvtpk(s1[10], s1[11]), b7 = cvtpk(s1[14], s1[15]); pl32swap(a7, b7);
      bf16x8 pf11 = mk8(a6, a7, b6, b7);

      // O^T += V^T * P   (lane owns q = qg in cols; rows = d)
#pragma unroll
      for (int sk = 0; sk < 4; ++sk) {
        const int s = sk >> 1, kc = sk & 1;
        const bf16x8 pf = (sk == 0) ? pf00 : (sk == 1) ? pf01 : (sk == 2) ? pf10 : pf11;
        {
          const int row = l31;
          bf16x8 vf = *(const bf16x8*)(Vlc + row * 128 +
                        ((((s << 2) + (kc << 1) + hi) ^ (row & 7)) << 4));
          Oa0 = __builtin_amdgcn_mfma_f32_32x32x16_bf16(vf, pf, Oa0, 0, 0, 0);
        }
        {
          const int row = 32 + l31;
          bf16x8 vf = *(const bf16x8*)(Vlc + row * 128 +
                        ((((s << 2) + (kc << 1) + hi) ^ (row & 7)) << 4));
          Oa1 = __builtin_amdgcn_mfma_f32_32x32x16_bf16(vf, pf, Oa1, 0, 0, 0);
        }
      }
    }
    __syncthreads();
    cur ^= 1;
  }

  // epilogue: normalize, transpose via LDS bounce, coalesced write
  unsigned short* ow = lds_all + wave * 2304;   // [32 q][72 d] padded
  const float inv = 1.0f / lsum;
#pragma unroll
  for (int r = 0; r < 16; ++r) {
    const int dl = (r & 3) + 8 * (r >> 2) + 4 * hi;
    ow[l31 * 72 + dl]      = f2b(Oa0[r] * inv);
    ow[l31 * 72 + 32 + dl] = f2b(Oa1[r] * inv);
  }
  __syncthreads();
#pragma unroll
  for (int it = 0; it < 4; ++it) {
    const int idx = it * 64 + lane;
    const int row = idx >> 3, blkk = idx & 7;
    bf16x8 v = *(const bf16x8*)(ow + row * 72 + blkk * 8);
    *(bf16x8*)(AO + (size_t)(b * S_ + q0w + row) * 2048 + h * 64 + blkk * 8) = v;
  }
}

extern "C" void kernel_launch(void* const* d_in, const int* in_sizes, int n_in,
                              void* d_out, int out_size, void* d_ws, size_t ws_size,
                              hipStream_t stream) {
  (void)in_sizes; (void)n_in; (void)out_size; (void)ws_size;
  const float* x    = (const float*)d_in[0];
  const float* wq   = (const float*)d_in[1];
  const float* wk   = (const float*)d_in[2];
  const float* wv   = (const float*)d_in[3];
  const float* wo   = (const float*)d_in[4];
  const float* cosg = (const float*)d_in[5];
  const float* sing = (const float*)d_in[6];

  char* ws = (char*)d_ws;
  unsigned short* xb   = (unsigned short*)(ws);                 // 16,777,216
  unsigned short* wcat = (unsigned short*)(ws + 16777216);      // 12,582,912
  unsigned short* wob  = (unsigned short*)(ws + 29360128);      //  8,388,608
  float*          qkv  = (float*)         (ws + 37748736);      // 50,331,648
  unsigned short* Qb   = (unsigned short*)(ws + 88080384);      // 16,777,216
  unsigned short* Kb   = (unsigned short*)(ws + 104857600);     //  4,194,304
  unsigned short* Vtb  = (unsigned short*)(ws + 109051904);     //  4,194,304
  unsigned short* AO   = xb;

  f2bf_kernel<<<8192, 256, 0, stream>>>(x, xb, 2097152);
  wcat_kernel<<<6144, 256, 0, stream>>>(wq, wk, wv, wcat);
  f2bf_kernel<<<4096, 256, 0, stream>>>(wo, wob, 1048576);

  gemm_bt<<<dim3(NQKV / 128, MROWS / 128), 256, 0, stream>>>(xb, wcat, qkv, MROWS, NQKV, DM);

  rope_kernel<<<MROWS, 256, 0, stream>>>(qkv, cosg, sing, Qb, Kb, Vtb);

  attn_kernel<<<dim3(S_ / 128, NH, B_), 256, 0, stream>>>(Qb, Kb, Vtb, AO);

  gemm_bt<<<dim3(DM / 128, MROWS / 128), 256, 0, stream>>>(AO, wob, (float*)d_out, MROWS, DM, DM);
}

// Round 3
// 295.374 us; speedup vs baseline: 1.3690x; 1.0285x over previous
//
#include <hip/hip_runtime.h>
#include <hip/hip_bf16.h>

#define B_   2
#define S_   2048
#define DM   2048
#define NH   32
#define NKV  8
#define HD   64
#define MROWS 4096   // B_*S_
#define NQKV  3072   // (NH+2*NKV)*HD

typedef __attribute__((ext_vector_type(8))) short bf16x8;
typedef __attribute__((ext_vector_type(4))) float f32x4;
typedef __attribute__((ext_vector_type(16))) float f32x16;

__device__ __forceinline__ unsigned short f2b(float f) {
  __hip_bfloat16 h = __float2bfloat16(f);
  return *reinterpret_cast<unsigned short*>(&h);
}

__device__ __forceinline__ void gload16(const void* g, void* l) {
  __builtin_amdgcn_global_load_lds((__attribute__((address_space(1))) void*)g,
                                   (__attribute__((address_space(3))) void*)l,
                                   16, 0, 0);
}

__device__ __forceinline__ unsigned cvtpk(float lo, float hi) {
  unsigned r;
  asm("v_cvt_pk_bf16_f32 %0, %1, %2" : "=v"(r) : "v"(lo), "v"(hi));
  return r;
}

__device__ __forceinline__ void pl32swap(unsigned& a, unsigned& b) {
  asm volatile("v_permlane32_swap_b32 %0, %1" : "+v"(a), "+v"(b));
}

__device__ __forceinline__ float exp2hw(float x) {   // 2^x via v_exp_f32
  float r;
  asm("v_exp_f32 %0, %1" : "=v"(r) : "v"(x));
  return r;
}

__device__ __forceinline__ bf16x8 mk8(unsigned w0, unsigned w1, unsigned w2, unsigned w3) {
  union { unsigned u[4]; bf16x8 v; } uu;
  uu.u[0] = w0; uu.u[1] = w1; uu.u[2] = w2; uu.u[3] = w3;
  return uu.v;
}

// ---------------- fp32 -> bf16 convert ----------------
__global__ __launch_bounds__(256) void f2bf_kernel(const float* __restrict__ in,
                                                   unsigned short* __restrict__ out, int n4) {
  int i = blockIdx.x * 256 + threadIdx.x;
  if (i < n4) {
    float4 v = reinterpret_cast<const float4*>(in)[i];
    ushort4 o;
    o.x = f2b(v.x); o.y = f2b(v.y); o.z = f2b(v.z); o.w = f2b(v.w);
    reinterpret_cast<ushort4*>(out)[i] = o;
  }
}

// ---------------- concat wq|wk|wv -> bf16 [3072][2048] ----------------
__global__ __launch_bounds__(256) void wcat_kernel(const float* __restrict__ wq,
                                                   const float* __restrict__ wk,
                                                   const float* __restrict__ wv,
                                                   unsigned short* __restrict__ out) {
  int i = blockIdx.x * 256 + threadIdx.x;
  int e = i * 4;
  int row = e >> 11;
  int col = e & 2047;
  const float* src;
  if (row < 2048)      src = wq + (size_t)row * 2048 + col;
  else if (row < 2560) src = wk + (size_t)(row - 2048) * 2048 + col;
  else                 src = wv + (size_t)(row - 2560) * 2048 + col;
  float4 v = *reinterpret_cast<const float4*>(src);
  ushort4 o;
  o.x = f2b(v.x); o.y = f2b(v.y); o.z = f2b(v.z); o.w = f2b(v.w);
  reinterpret_cast<ushort4*>(out)[i] = o;
}

// ---------------- GEMM C[M,N] = A[M,K] * B[N,K]^T  (bf16 in, fp32 out) ----------------
__global__ __launch_bounds__(256) void gemm_bt(const unsigned short* __restrict__ A,
                                               const unsigned short* __restrict__ Bm,
                                               float* __restrict__ C,
                                               int M, int N, int K) {
  __shared__ unsigned short Ab[128 * 64];
  __shared__ unsigned short Bb[128 * 64];
  const int tid = threadIdx.x;
  const int wave = tid >> 6, lane = tid & 63;
  const int wr = wave >> 1, wc = wave & 1;
  const int rowbase = blockIdx.y * 128;
  const int colbase = blockIdx.x * 128;

  f32x4 acc[4][4];
#pragma unroll
  for (int a = 0; a < 4; a++)
#pragma unroll
    for (int b2 = 0; b2 < 4; b2++) acc[a][b2] = (f32x4){0.f, 0.f, 0.f, 0.f};

  const int r8 = lane >> 3;
  const int c8 = (lane & 7) * 8;
  const unsigned short* Ag = A + (size_t)rowbase * K;
  const unsigned short* Bg = Bm + (size_t)colbase * K;

  for (int k0 = 0; k0 < K; k0 += 64) {
#pragma unroll
    for (int c = 0; c < 4; c++) {
      int rowg = (wave * 4 + c) * 8;
      gload16(Ag + (size_t)(rowg + r8) * K + k0 + c8, &Ab[rowg * 64]);
      gload16(Bg + (size_t)(rowg + r8) * K + k0 + c8, &Bb[rowg * 64]);
    }
    __syncthreads();
#pragma unroll
    for (int kk = 0; kk < 64; kk += 32) {
      bf16x8 af[4], bfr[4];
#pragma unroll
      for (int mt = 0; mt < 4; mt++)
        af[mt] = *reinterpret_cast<const bf16x8*>(
            &Ab[(wr * 64 + mt * 16 + (lane & 15)) * 64 + kk + (lane >> 4) * 8]);
#pragma unroll
      for (int nt = 0; nt < 4; nt++)
        bfr[nt] = *reinterpret_cast<const bf16x8*>(
            &Bb[(wc * 64 + nt * 16 + (lane & 15)) * 64 + kk + (lane >> 4) * 8]);
#pragma unroll
      for (int mt = 0; mt < 4; mt++)
#pragma unroll
        for (int nt = 0; nt < 4; nt++)
          acc[mt][nt] = __builtin_amdgcn_mfma_f32_16x16x32_bf16(af[mt], bfr[nt], acc[mt][nt], 0, 0, 0);
    }
    __syncthreads();
  }

  const int orow = rowbase + wr * 64, ocol = colbase + wc * 64;
#pragma unroll
  for (int mt = 0; mt < 4; mt++)
#pragma unroll
    for (int nt = 0; nt < 4; nt++)
#pragma unroll
      for (int r = 0; r < 4; r++)
        C[(size_t)(orow + mt * 16 + (lane >> 4) * 4 + r) * N + ocol + nt * 16 + (lane & 15)] =
            acc[mt][nt][r];
}

// ---------------- RoPE + layout: qkv fp32 -> Q/K/V^T bf16 ----------------
// Q is pre-scaled by 0.125*log2(e) so attention scores land in exp2 domain.
#define QSCALE 0.18033688011112042f
__global__ __launch_bounds__(256) void rope_kernel(const float* __restrict__ qkv,
                                                   const float* __restrict__ cosg,
                                                   const float* __restrict__ sing,
                                                   unsigned short* __restrict__ Qb,
                                                   unsigned short* __restrict__ Kb,
                                                   unsigned short* __restrict__ Vtb) {
  const int row = blockIdx.x;              // b*S + s
  const int b = row >> 11, s = row & 2047;
  __shared__ float cs[32], sn[32];
  if (threadIdx.x < 32) {
    cs[threadIdx.x] = cosg[s * 32 + threadIdx.x];
    sn[threadIdx.x] = sing[s * 32 + threadIdx.x];
  }
  __syncthreads();
  const float* qr = qkv + (size_t)row * NQKV;
  const int t = threadIdx.x;

  for (int pid = t; pid < 1024; pid += 256) {
    const int h = pid >> 5, i = pid & 31, i2 = i >> 1;
    float qa = qr[h * 64 + i], qb2 = qr[h * 64 + i + 32];
    size_t base = ((size_t)(b * NH + h) * S_ + s) * HD;
    Qb[base + i]      = f2b((qa * cs[i2] - qb2 * sn[i2]) * QSCALE);
    Qb[base + i + 32] = f2b((qb2 * cs[16 + i2] + qa * sn[16 + i2]) * QSCALE);
  }
  {
    const int h = t >> 5, i = t & 31, i2 = i >> 1;
    float ka = qr[2048 + h * 64 + i], kb2 = qr[2048 + h * 64 + i + 32];
    size_t base = ((size_t)(b * NKV + h) * S_ + s) * HD;
    Kb[base + i]      = f2b(ka * cs[i2] - kb2 * sn[i2]);
    Kb[base + i + 32] = f2b(kb2 * cs[16 + i2] + ka * sn[16 + i2]);
  }
  for (int j = t; j < 512; j += 256) {
    const int h = j >> 6, d = j & 63;
    Vtb[((size_t)(b * NKV + h) * HD + d) * S_ + s] = f2b(qr[2560 + j]);
  }
}

// ---------------- Flash attention: 4 waves x 32 q-rows, KV tiles 64, swapped QK ----------------
__device__ __forceinline__ void stage_kv(const unsigned short* __restrict__ Kbase,
                                         const unsigned short* __restrict__ Vbase,
                                         unsigned short* Kl, unsigned short* Vl,
                                         int j0, int wave, int lane) {
#pragma unroll
  for (int tt = 0; tt < 2; ++tt) {
    int slot = (wave * 2 + tt) * 64 + lane;
    int row = slot >> 3, blk = slot & 7;
    int sb = ((blk ^ (row & 7)) << 3);          // pre-swizzled global source (rule 21)
    gload16(Kbase + (size_t)(j0 + row) * HD + sb, Kl + (wave * 2 + tt) * 512);
    gload16(Vbase + (size_t)row * S_ + j0 + sb, Vl + (wave * 2 + tt) * 512);
  }
}

__global__ __launch_bounds__(256) void attn_kernel(const unsigned short* __restrict__ Q,
                                                   const unsigned short* __restrict__ Kg,
                                                   const unsigned short* __restrict__ Vt,
                                                   unsigned short* __restrict__ AO) {
  // LPT: longest q-blocks first (blockIdx.x ascending -> qbi descending)
  const int qbi = (S_ / 128 - 1) - blockIdx.x;
  const int h = blockIdx.y, b = blockIdx.z;
  const int hk = h >> 2;
  const int qb = qbi * 128;
  __shared__ unsigned short lds_all[16384];   // [2 buf][K 4096] + [2 buf][V 4096]
  const int tid = threadIdx.x, wave = tid >> 6, lane = tid & 63;
  const int l31 = lane & 31, hi = lane >> 5;
  const int q0w = qb + wave * 32;
  const int qg = q0w + l31;

  const unsigned short* Qbase = Q + (size_t)(b * NH + h) * S_ * HD;
  const unsigned short* Kbase = Kg + (size_t)(b * NKV + hk) * S_ * HD;
  const unsigned short* Vbase = Vt + (size_t)(b * NKV + hk) * HD * S_;

  bf16x8 qf[4];
#pragma unroll
  for (int c = 0; c < 4; ++c)
    qf[c] = *reinterpret_cast<const bf16x8*>(Qbase + (size_t)qg * HD + c * 16 + hi * 8);

  f32x16 Oa0 = {}, Oa1 = {};
  float m_old = -INFINITY, lsum = 0.f;

  const int NT = (qb + 128) / 64;

  stage_kv(Kbase, Vbase, lds_all, lds_all + 8192, 0, wave, lane);
  __syncthreads();
  int cur = 0;

  for (int t = 0; t < NT; ++t) {
    const int j0 = t * 64;
    if (t + 1 < NT)
      stage_kv(Kbase, Vbase, lds_all + (cur ^ 1) * 4096, lds_all + 8192 + (cur ^ 1) * 4096,
               (t + 1) * 64, wave, lane);

    if (j0 < q0w + 32) {
      const char* Klc = (const char*)(lds_all + cur * 4096);
      const char* Vlc = (const char*)(lds_all + 8192 + cur * 4096);

      // S = K * Q  (scores transposed: lane owns q = qg; scores pre-scaled to exp2 domain)
      f32x16 s0 = {}, s1 = {};
      __builtin_amdgcn_s_setprio(1);
#pragma unroll
      for (int c = 0; c < 4; ++c) {
        const int r0 = l31;
        bf16x8 kf = *(const bf16x8*)(Klc + r0 * 128 + ((((c << 1) + hi) ^ (r0 & 7)) << 4));
        s0 = __builtin_amdgcn_mfma_f32_32x32x16_bf16(kf, qf[c], s0, 0, 0, 0);
      }
#pragma unroll
      for (int c = 0; c < 4; ++c) {
        const int r1 = 32 + l31;
        bf16x8 kf = *(const bf16x8*)(Klc + r1 * 128 + ((((c << 1) + hi) ^ (r1 & 7)) << 4));
        s1 = __builtin_amdgcn_mfma_f32_32x32x16_bf16(kf, qf[c], s1, 0, 0, 0);
      }
      __builtin_amdgcn_s_setprio(0);

      // causal mask (diagonal tiles only; scores already scaled)
      const bool need_mask = (j0 + 63 > q0w);
      const int kb0 = j0 + 4 * hi, kb1 = j0 + 32 + 4 * hi;
      if (need_mask) {
#pragma unroll
        for (int r = 0; r < 16; ++r) {
          const int ko = (r & 3) + 8 * (r >> 2);
          if (kb0 + ko > qg) s0[r] = -INFINITY;
          if (kb1 + ko > qg) s1[r] = -INFINITY;
        }
      }

      // tree row-max (4 parallel chains)
      float a0 = fmaxf(s0[0], s1[0]), a1 = fmaxf(s0[1], s1[1]);
      float a2 = fmaxf(s0[2], s1[2]), a3 = fmaxf(s0[3], s1[3]);
#pragma unroll
      for (int r = 4; r < 16; r += 4) {
        a0 = fmaxf(a0, fmaxf(s0[r], s1[r]));
        a1 = fmaxf(a1, fmaxf(s0[r + 1], s1[r + 1]));
        a2 = fmaxf(a2, fmaxf(s0[r + 2], s1[r + 2]));
        a3 = fmaxf(a3, fmaxf(s0[r + 3], s1[r + 3]));
      }
      float mxt = fmaxf(fmaxf(a0, a1), fmaxf(a2, a3));
      mxt = fmaxf(mxt, __shfl_xor(mxt, 32, 64));

      // defer-rescale (T13): skip O-rescale while tile max stays within 2^8
      if (!__all(mxt - m_old <= 8.f)) {
        float mnew = fmaxf(m_old, mxt);
        float corr = exp2hw(m_old - mnew);
        m_old = mnew;
        lsum *= corr;
#pragma unroll
        for (int r = 0; r < 16; ++r) { Oa0[r] *= corr; Oa1[r] *= corr; }
      }

      // p = 2^(s - m); tree sum (4 parallel chains)
      float t0 = 0.f, t1 = 0.f, t2 = 0.f, t3 = 0.f;
#pragma unroll
      for (int r = 0; r < 16; r += 4) {
        s0[r]     = exp2hw(s0[r] - m_old);     t0 += s0[r];
        s0[r + 1] = exp2hw(s0[r + 1] - m_old); t1 += s0[r + 1];
        s0[r + 2] = exp2hw(s0[r + 2] - m_old); t2 += s0[r + 2];
        s0[r + 3] = exp2hw(s0[r + 3] - m_old); t3 += s0[r + 3];
      }
#pragma unroll
      for (int r = 0; r < 16; r += 4) {
        s1[r]     = exp2hw(s1[r] - m_old);     t0 += s1[r];
        s1[r + 1] = exp2hw(s1[r + 1] - m_old); t1 += s1[r + 1];
        s1[r + 2] = exp2hw(s1[r + 2] - m_old); t2 += s1[r + 2];
        s1[r + 3] = exp2hw(s1[r + 3] - m_old); t3 += s1[r + 3];
      }
      float rs = (t0 + t1) + (t2 + t3);
      rs += __shfl_xor(rs, 32, 64);
      lsum += rs;

      // P -> bf16 B-fragments in-register (cvt_pk + permlane32_swap)
      unsigned a0u = cvtpk(s0[0], s0[1]),  b0u = cvtpk(s0[4], s0[5]);  pl32swap(a0u, b0u);
      unsigned a1u = cvtpk(s0[2], s0[3]),  b1u = cvtpk(s0[6], s0[7]);  pl32swap(a1u, b1u);
      bf16x8 pf00 = mk8(a0u, a1u, b0u, b1u);
      unsigned a2u = cvtpk(s0[8], s0[9]),  b2u = cvtpk(s0[12], s0[13]); pl32swap(a2u, b2u);
      unsigned a3u = cvtpk(s0[10], s0[11]), b3u = cvtpk(s0[14], s0[15]); pl32swap(a3u, b3u);
      bf16x8 pf01 = mk8(a2u, a3u, b2u, b3u);
      unsigned a4u = cvtpk(s1[0], s1[1]),  b4u = cvtpk(s1[4], s1[5]);  pl32swap(a4u, b4u);
      unsigned a5u = cvtpk(s1[2], s1[3]),  b5u = cvtpk(s1[6], s1[7]);  pl32swap(a5u, b5u);
      bf16x8 pf10 = mk8(a4u, a5u, b4u, b5u);
      unsigned a6u = cvtpk(s1[8], s1[9]),  b6u = cvtpk(s1[12], s1[13]); pl32swap(a6u, b6u);
      unsigned a7u = cvtpk(s1[10], s1[11]), b7u = cvtpk(s1[14], s1[15]); pl32swap(a7u, b7u);
      bf16x8 pf11 = mk8(a6u, a7u, b6u, b7u);

      // O^T += V^T * P   (lane owns q = qg in cols; rows = d)
      __builtin_amdgcn_s_setprio(1);
#pragma unroll
      for (int sk = 0; sk < 4; ++sk) {
        const int s = sk >> 1, kc = sk & 1;
        const bf16x8 pf = (sk == 0) ? pf00 : (sk == 1) ? pf01 : (sk == 2) ? pf10 : pf11;
        {
          const int row = l31;
          bf16x8 vf = *(const bf16x8*)(Vlc + row * 128 +
                        ((((s << 2) + (kc << 1) + hi) ^ (row & 7)) << 4));
          Oa0 = __builtin_amdgcn_mfma_f32_32x32x16_bf16(vf, pf, Oa0, 0, 0, 0);
        }
        {
          const int row = 32 + l31;
          bf16x8 vf = *(const bf16x8*)(Vlc + row * 128 +
                        ((((s << 2) + (kc << 1) + hi) ^ (row & 7)) << 4));
          Oa1 = __builtin_amdgcn_mfma_f32_32x32x16_bf16(vf, pf, Oa1, 0, 0, 0);
        }
      }
      __builtin_amdgcn_s_setprio(0);
    }
    __syncthreads();
    cur ^= 1;
  }

  // epilogue: normalize, transpose via LDS bounce, coalesced write
  unsigned short* ow = lds_all + wave * 2304;   // [32 q][72 d] padded
  const float inv = 1.0f / lsum;
#pragma unroll
  for (int r = 0; r < 16; ++r) {
    const int dl = (r & 3) + 8 * (r >> 2) + 4 * hi;
    ow[l31 * 72 + dl]      = f2b(Oa0[r] * inv);
    ow[l31 * 72 + 32 + dl] = f2b(Oa1[r] * inv);
  }
  __syncthreads();
#pragma unroll
  for (int it = 0; it < 4; ++it) {
    const int idx = it * 64 + lane;
    const int row = idx >> 3, blkk = idx & 7;
    bf16x8 v = *(const bf16x8*)(ow + row * 72 + blkk * 8);
    *(bf16x8*)(AO + (size_t)(b * S_ + qb + wave * 32 + row) * 2048 + h * 64 + blkk * 8) = v;
  }
}

extern "C" void kernel_launch(void* const* d_in, const int* in_sizes, int n_in,
                              void* d_out, int out_size, void* d_ws, size_t ws_size,
                              hipStream_t stream) {
  (void)in_sizes; (void)n_in; (void)out_size; (void)ws_size;
  const float* x    = (const float*)d_in[0];
  const float* wq   = (const float*)d_in[1];
  const float* wk   = (const float*)d_in[2];
  const float* wv   = (const float*)d_in[3];
  const float* wo   = (const float*)d_in[4];
  const float* cosg = (const float*)d_in[5];
  const float* sing = (const float*)d_in[6];

  char* ws = (char*)d_ws;
  unsigned short* xb   = (unsigned short*)(ws);                 // 16,777,216
  unsigned short* wcat = (unsigned short*)(ws + 16777216);      // 12,582,912
  unsigned short* wob  = (unsigned short*)(ws + 29360128);      //  8,388,608
  float*          qkv  = (float*)         (ws + 37748736);      // 50,331,648
  unsigned short* Qb   = (unsigned short*)(ws + 88080384);      // 16,777,216
  unsigned short* Kb   = (unsigned short*)(ws + 104857600);     //  4,194,304
  unsigned short* Vtb  = (unsigned short*)(ws + 109051904);     //  4,194,304
  unsigned short* AO   = xb;

  f2bf_kernel<<<8192, 256, 0, stream>>>(x, xb, 2097152);
  wcat_kernel<<<6144, 256, 0, stream>>>(wq, wk, wv, wcat);
  f2bf_kernel<<<4096, 256, 0, stream>>>(wo, wob, 1048576);

  gemm_bt<<<dim3(NQKV / 128, MROWS / 128), 256, 0, stream>>>(xb, wcat, qkv, MROWS, NQKV, DM);

  rope_kernel<<<MROWS, 256, 0, stream>>>(qkv, cosg, sing, Qb, Kb, Vtb);

  attn_kernel<<<dim3(S_ / 128, NH, B_), 256, 0, stream>>>(Qb, Kb, Vtb, AO);

  gemm_bt<<<dim3(DM / 128, MROWS / 128), 256, 0, stream>>>(AO, wob, (float*)d_out, MROWS, DM, DM);
}

// Round 4
// 256.132 us; speedup vs baseline: 1.5787x; 1.1532x over previous
//
#include <hip/hip_runtime.h>
#include <hip/hip_bf16.h>

#define B_   2
#define S_   2048
#define DM   2048
#define NH   32
#define NKV  8
#define HD   64
#define MROWS 4096   // B_*S_
#define NQKV  3072   // (NH+2*NKV)*HD

typedef __attribute__((ext_vector_type(8))) short bf16x8;
typedef __attribute__((ext_vector_type(4))) float f32x4;
typedef __attribute__((ext_vector_type(16))) float f32x16;

__device__ __forceinline__ unsigned short f2b(float f) {
  __hip_bfloat16 h = __float2bfloat16(f);
  return *reinterpret_cast<unsigned short*>(&h);
}

__device__ __forceinline__ void gload16(const void* g, void* l) {
  __builtin_amdgcn_global_load_lds((__attribute__((address_space(1))) void*)g,
                                   (__attribute__((address_space(3))) void*)l,
                                   16, 0, 0);
}

__device__ __forceinline__ unsigned cvtpk(float lo, float hi) {
  unsigned r;
  asm("v_cvt_pk_bf16_f32 %0, %1, %2" : "=v"(r) : "v"(lo), "v"(hi));
  return r;
}

__device__ __forceinline__ void pl32swap(unsigned& a, unsigned& b) {
  asm volatile("v_permlane32_swap_b32 %0, %1" : "+v"(a), "+v"(b));
}

__device__ __forceinline__ float exp2hw(float x) {   // 2^x via v_exp_f32
  float r;
  asm("v_exp_f32 %0, %1" : "=v"(r) : "v"(x));
  return r;
}

__device__ __forceinline__ bf16x8 mk8(unsigned w0, unsigned w1, unsigned w2, unsigned w3) {
  union { unsigned u[4]; bf16x8 v; } uu;
  uu.u[0] = w0; uu.u[1] = w1; uu.u[2] = w2; uu.u[3] = w3;
  return uu.v;
}

// ---------------- fp32 -> bf16 convert ----------------
__global__ __launch_bounds__(256) void f2bf_kernel(const float* __restrict__ in,
                                                   unsigned short* __restrict__ out, int n4) {
  int i = blockIdx.x * 256 + threadIdx.x;
  if (i < n4) {
    float4 v = reinterpret_cast<const float4*>(in)[i];
    ushort4 o;
    o.x = f2b(v.x); o.y = f2b(v.y); o.z = f2b(v.z); o.w = f2b(v.w);
    reinterpret_cast<ushort4*>(out)[i] = o;
  }
}

// ---------------- concat wq|wk|wv -> bf16 [3072][2048] ----------------
__global__ __launch_bounds__(256) void wcat_kernel(const float* __restrict__ wq,
                                                   const float* __restrict__ wk,
                                                   const float* __restrict__ wv,
                                                   unsigned short* __restrict__ out) {
  int i = blockIdx.x * 256 + threadIdx.x;
  int e = i * 4;
  int row = e >> 11;
  int col = e & 2047;
  const float* src;
  if (row < 2048)      src = wq + (size_t)row * 2048 + col;
  else if (row < 2560) src = wk + (size_t)(row - 2048) * 2048 + col;
  else                 src = wv + (size_t)(row - 2560) * 2048 + col;
  float4 v = *reinterpret_cast<const float4*>(src);
  ushort4 o;
  o.x = f2b(v.x); o.y = f2b(v.y); o.z = f2b(v.z); o.w = f2b(v.w);
  reinterpret_cast<ushort4*>(out)[i] = o;
}

// ---------------- GEMM C[M,N] = A[M,K] * B[N,K]^T  (bf16 in, fp32 out) ----------------
__global__ __launch_bounds__(256) void gemm_bt(const unsigned short* __restrict__ A,
                                               const unsigned short* __restrict__ Bm,
                                               float* __restrict__ C,
                                               int M, int N, int K) {
  __shared__ unsigned short Ab[128 * 64];
  __shared__ unsigned short Bb[128 * 64];
  const int tid = threadIdx.x;
  const int wave = tid >> 6, lane = tid & 63;
  const int wr = wave >> 1, wc = wave & 1;
  const int rowbase = blockIdx.y * 128;
  const int colbase = blockIdx.x * 128;

  f32x4 acc[4][4];
#pragma unroll
  for (int a = 0; a < 4; a++)
#pragma unroll
    for (int b2 = 0; b2 < 4; b2++) acc[a][b2] = (f32x4){0.f, 0.f, 0.f, 0.f};

  const int r8 = lane >> 3;
  const int c8 = (lane & 7) * 8;
  const unsigned short* Ag = A + (size_t)rowbase * K;
  const unsigned short* Bg = Bm + (size_t)colbase * K;

  for (int k0 = 0; k0 < K; k0 += 64) {
#pragma unroll
    for (int c = 0; c < 4; c++) {
      int rowg = (wave * 4 + c) * 8;
      gload16(Ag + (size_t)(rowg + r8) * K + k0 + c8, &Ab[rowg * 64]);
      gload16(Bg + (size_t)(rowg + r8) * K + k0 + c8, &Bb[rowg * 64]);
    }
    __syncthreads();
#pragma unroll
    for (int kk = 0; kk < 64; kk += 32) {
      bf16x8 af[4], bfr[4];
#pragma unroll
      for (int mt = 0; mt < 4; mt++)
        af[mt] = *reinterpret_cast<const bf16x8*>(
            &Ab[(wr * 64 + mt * 16 + (lane & 15)) * 64 + kk + (lane >> 4) * 8]);
#pragma unroll
      for (int nt = 0; nt < 4; nt++)
        bfr[nt] = *reinterpret_cast<const bf16x8*>(
            &Bb[(wc * 64 + nt * 16 + (lane & 15)) * 64 + kk + (lane >> 4) * 8]);
#pragma unroll
      for (int mt = 0; mt < 4; mt++)
#pragma unroll
        for (int nt = 0; nt < 4; nt++)
          acc[mt][nt] = __builtin_amdgcn_mfma_f32_16x16x32_bf16(af[mt], bfr[nt], acc[mt][nt], 0, 0, 0);
    }
    __syncthreads();
  }

  const int orow = rowbase + wr * 64, ocol = colbase + wc * 64;
#pragma unroll
  for (int mt = 0; mt < 4; mt++)
#pragma unroll
    for (int nt = 0; nt < 4; nt++)
#pragma unroll
      for (int r = 0; r < 4; r++)
        C[(size_t)(orow + mt * 16 + (lane >> 4) * 4 + r) * N + ocol + nt * 16 + (lane & 15)] =
            acc[mt][nt][r];
}

// ---------------- RoPE + layout: qkv fp32 -> Q/K/V^T bf16 ----------------
// Q is pre-scaled by 0.125*log2(e) so attention scores land in exp2 domain.
#define QSCALE 0.18033688011112042f
__global__ __launch_bounds__(256) void rope_kernel(const float* __restrict__ qkv,
                                                   const float* __restrict__ cosg,
                                                   const float* __restrict__ sing,
                                                   unsigned short* __restrict__ Qb,
                                                   unsigned short* __restrict__ Kb,
                                                   unsigned short* __restrict__ Vtb) {
  const int row = blockIdx.x;              // b*S + s
  const int b = row >> 11, s = row & 2047;
  __shared__ float cs[32], sn[32];
  if (threadIdx.x < 32) {
    cs[threadIdx.x] = cosg[s * 32 + threadIdx.x];
    sn[threadIdx.x] = sing[s * 32 + threadIdx.x];
  }
  __syncthreads();
  const float* qr = qkv + (size_t)row * NQKV;
  const int t = threadIdx.x;

  for (int pid = t; pid < 1024; pid += 256) {
    const int h = pid >> 5, i = pid & 31, i2 = i >> 1;
    float qa = qr[h * 64 + i], qb2 = qr[h * 64 + i + 32];
    size_t base = ((size_t)(b * NH + h) * S_ + s) * HD;
    Qb[base + i]      = f2b((qa * cs[i2] - qb2 * sn[i2]) * QSCALE);
    Qb[base + i + 32] = f2b((qb2 * cs[16 + i2] + qa * sn[16 + i2]) * QSCALE);
  }
  {
    const int h = t >> 5, i = t & 31, i2 = i >> 1;
    float ka = qr[2048 + h * 64 + i], kb2 = qr[2048 + h * 64 + i + 32];
    size_t base = ((size_t)(b * NKV + h) * S_ + s) * HD;
    Kb[base + i]      = f2b(ka * cs[i2] - kb2 * sn[i2]);
    Kb[base + i + 32] = f2b(kb2 * cs[16 + i2] + ka * sn[16 + i2]);
  }
  for (int j = t; j < 512; j += 256) {
    const int h = j >> 6, d = j & 63;
    Vtb[((size_t)(b * NKV + h) * HD + d) * S_ + s] = f2b(qr[2560 + j]);
  }
}

// ---------------- Flash attention: paired q-regions, 34 KV-tiles per block uniform ----------------
__device__ __forceinline__ void stage_kv(const unsigned short* __restrict__ Kbase,
                                         const unsigned short* __restrict__ Vbase,
                                         unsigned short* Kl, unsigned short* Vl,
                                         int j0, int wave, int lane) {
#pragma unroll
  for (int tt = 0; tt < 2; ++tt) {
    int slot = (wave * 2 + tt) * 64 + lane;
    int row = slot >> 3, blk = slot & 7;
    int sb = ((blk ^ (row & 7)) << 3);          // pre-swizzled global source (rule 21)
    gload16(Kbase + (size_t)(j0 + row) * HD + sb, Kl + (wave * 2 + tt) * 512);
    gload16(Vbase + (size_t)row * S_ + j0 + sb, Vl + (wave * 2 + tt) * 512);
  }
}

__global__ __launch_bounds__(256) void attn_kernel(const unsigned short* __restrict__ Q,
                                                   const unsigned short* __restrict__ Kg,
                                                   const unsigned short* __restrict__ Vt,
                                                   unsigned short* __restrict__ AO) {
  // paired q-regions: block pr handles qbi = 15-pr (long, first) then qbi = pr (short).
  // total KV tiles = 2*(16-pr) + 2*(pr+1) = 34 for every block -> uniform load.
  const int pr = blockIdx.x, h = blockIdx.y, b = blockIdx.z;
  const int hk = h >> 2;
  __shared__ unsigned short kv_lds[16384];   // [2 buf][K 4KB] + [2 buf][V 4KB]
  __shared__ unsigned short ow_lds[9216];    // epilogue bounce [4 waves][32][72]
  const int tid = threadIdx.x, wave = tid >> 6, lane = tid & 63;
  const int l31 = lane & 31, hi = lane >> 5;

  const unsigned short* Qbase = Q + (size_t)(b * NH + h) * S_ * HD;
  const unsigned short* Kbase = Kg + (size_t)(b * NKV + hk) * S_ * HD;
  const unsigned short* Vbase = Vt + (size_t)(b * NKV + hk) * HD * S_;

  const int NT_B = 2 * (16 - pr);   // long region tile count
  const int NTtot = 34;

  stage_kv(Kbase, Vbase, kv_lds, kv_lds + 8192, 0, wave, lane);
  __syncthreads();
  int cur = 0;
  int tlin = 0;

  for (int rg = 0; rg < 2; ++rg) {
    const int qbi = rg == 0 ? (15 - pr) : pr;
    const int qb = qbi * 128;
    const int NT = 2 * (qbi + 1);
    const int q0w = qb + wave * 32;
    const int qg = q0w + l31;

    bf16x8 qf[4];
#pragma unroll
    for (int c = 0; c < 4; ++c)
      qf[c] = *reinterpret_cast<const bf16x8*>(Qbase + (size_t)qg * HD + c * 16 + hi * 8);

    f32x16 Oa0 = {}, Oa1 = {};
    float m_old = -INFINITY, lsum = 0.f;

    for (int t = 0; t < NT; ++t, ++tlin) {
      const int j0 = t * 64;
      const int tn = tlin + 1;
      if (tn < NTtot) {
        const int j0n = (tn < NT_B ? tn : tn - NT_B) * 64;
        stage_kv(Kbase, Vbase, kv_lds + (cur ^ 1) * 4096, kv_lds + 8192 + (cur ^ 1) * 4096,
                 j0n, wave, lane);
      }

      if (j0 < q0w + 32) {
        const char* Klc = (const char*)(kv_lds + cur * 4096);
        const char* Vlc = (const char*)(kv_lds + 8192 + cur * 4096);

        // S = K * Q  (lane owns q = qg; scores pre-scaled to exp2 domain)
        f32x16 s0 = {}, s1 = {};
        __builtin_amdgcn_s_setprio(1);
#pragma unroll
        for (int c = 0; c < 4; ++c) {
          const int r0 = l31;
          bf16x8 kf = *(const bf16x8*)(Klc + r0 * 128 + ((((c << 1) + hi) ^ (r0 & 7)) << 4));
          s0 = __builtin_amdgcn_mfma_f32_32x32x16_bf16(kf, qf[c], s0, 0, 0, 0);
        }
#pragma unroll
        for (int c = 0; c < 4; ++c) {
          const int r1 = 32 + l31;
          bf16x8 kf = *(const bf16x8*)(Klc + r1 * 128 + ((((c << 1) + hi) ^ (r1 & 7)) << 4));
          s1 = __builtin_amdgcn_mfma_f32_32x32x16_bf16(kf, qf[c], s1, 0, 0, 0);
        }
        __builtin_amdgcn_s_setprio(0);

        // causal mask (diagonal tiles only)
        const bool need_mask = (j0 + 63 > q0w);
        const int kb0 = j0 + 4 * hi, kb1 = j0 + 32 + 4 * hi;
        if (need_mask) {
#pragma unroll
          for (int r = 0; r < 16; ++r) {
            const int ko = (r & 3) + 8 * (r >> 2);
            if (kb0 + ko > qg) s0[r] = -INFINITY;
            if (kb1 + ko > qg) s1[r] = -INFINITY;
          }
        }

        // tree row-max (4 parallel chains)
        float a0 = fmaxf(s0[0], s1[0]), a1 = fmaxf(s0[1], s1[1]);
        float a2 = fmaxf(s0[2], s1[2]), a3 = fmaxf(s0[3], s1[3]);
#pragma unroll
        for (int r = 4; r < 16; r += 4) {
          a0 = fmaxf(a0, fmaxf(s0[r], s1[r]));
          a1 = fmaxf(a1, fmaxf(s0[r + 1], s1[r + 1]));
          a2 = fmaxf(a2, fmaxf(s0[r + 2], s1[r + 2]));
          a3 = fmaxf(a3, fmaxf(s0[r + 3], s1[r + 3]));
        }
        float mxt = fmaxf(fmaxf(a0, a1), fmaxf(a2, a3));
        mxt = fmaxf(mxt, __shfl_xor(mxt, 32, 64));

        // defer-rescale (T13)
        if (!__all(mxt - m_old <= 8.f)) {
          float mnew = fmaxf(m_old, mxt);
          float corr = exp2hw(m_old - mnew);
          m_old = mnew;
          lsum *= corr;
#pragma unroll
          for (int r = 0; r < 16; ++r) { Oa0[r] *= corr; Oa1[r] *= corr; }
        }

        // p = 2^(s - m); tree sum
        float t0 = 0.f, t1 = 0.f, t2 = 0.f, t3 = 0.f;
#pragma unroll
        for (int r = 0; r < 16; r += 4) {
          s0[r]     = exp2hw(s0[r] - m_old);     t0 += s0[r];
          s0[r + 1] = exp2hw(s0[r + 1] - m_old); t1 += s0[r + 1];
          s0[r + 2] = exp2hw(s0[r + 2] - m_old); t2 += s0[r + 2];
          s0[r + 3] = exp2hw(s0[r + 3] - m_old); t3 += s0[r + 3];
        }
#pragma unroll
        for (int r = 0; r < 16; r += 4) {
          s1[r]     = exp2hw(s1[r] - m_old);     t0 += s1[r];
          s1[r + 1] = exp2hw(s1[r + 1] - m_old); t1 += s1[r + 1];
          s1[r + 2] = exp2hw(s1[r + 2] - m_old); t2 += s1[r + 2];
          s1[r + 3] = exp2hw(s1[r + 3] - m_old); t3 += s1[r + 3];
        }
        float rs = (t0 + t1) + (t2 + t3);
        rs += __shfl_xor(rs, 32, 64);
        lsum += rs;

        // P -> bf16 B-fragments in-register
        unsigned a0u = cvtpk(s0[0], s0[1]),  b0u = cvtpk(s0[4], s0[5]);  pl32swap(a0u, b0u);
        unsigned a1u = cvtpk(s0[2], s0[3]),  b1u = cvtpk(s0[6], s0[7]);  pl32swap(a1u, b1u);
        bf16x8 pf00 = mk8(a0u, a1u, b0u, b1u);
        unsigned a2u = cvtpk(s0[8], s0[9]),  b2u = cvtpk(s0[12], s0[13]); pl32swap(a2u, b2u);
        unsigned a3u = cvtpk(s0[10], s0[11]), b3u = cvtpk(s0[14], s0[15]); pl32swap(a3u, b3u);
        bf16x8 pf01 = mk8(a2u, a3u, b2u, b3u);
        unsigned a4u = cvtpk(s1[0], s1[1]),  b4u = cvtpk(s1[4], s1[5]);  pl32swap(a4u, b4u);
        unsigned a5u = cvtpk(s1[2], s1[3]),  b5u = cvtpk(s1[6], s1[7]);  pl32swap(a5u, b5u);
        bf16x8 pf10 = mk8(a4u, a5u, b4u, b5u);
        unsigned a6u = cvtpk(s1[8], s1[9]),  b6u = cvtpk(s1[12], s1[13]); pl32swap(a6u, b6u);
        unsigned a7u = cvtpk(s1[10], s1[11]), b7u = cvtpk(s1[14], s1[15]); pl32swap(a7u, b7u);
        bf16x8 pf11 = mk8(a6u, a7u, b6u, b7u);

        // O^T += V^T * P
        __builtin_amdgcn_s_setprio(1);
#pragma unroll
        for (int sk = 0; sk < 4; ++sk) {
          const int s = sk >> 1, kc = sk & 1;
          const bf16x8 pf = (sk == 0) ? pf00 : (sk == 1) ? pf01 : (sk == 2) ? pf10 : pf11;
          {
            const int row = l31;
            bf16x8 vf = *(const bf16x8*)(Vlc + row * 128 +
                          ((((s << 2) + (kc << 1) + hi) ^ (row & 7)) << 4));
            Oa0 = __builtin_amdgcn_mfma_f32_32x32x16_bf16(vf, pf, Oa0, 0, 0, 0);
          }
          {
            const int row = 32 + l31;
            bf16x8 vf = *(const bf16x8*)(Vlc + row * 128 +
                          ((((s << 2) + (kc << 1) + hi) ^ (row & 7)) << 4));
            Oa1 = __builtin_amdgcn_mfma_f32_32x32x16_bf16(vf, pf, Oa1, 0, 0, 0);
          }
        }
        __builtin_amdgcn_s_setprio(0);
      }
      __syncthreads();
      cur ^= 1;
    }

    // epilogue: normalize, transpose via dedicated LDS bounce, coalesced write
    unsigned short* ow = ow_lds + wave * 2304;   // [32 q][72 d]
    const float inv = 1.0f / lsum;
#pragma unroll
    for (int r = 0; r < 16; ++r) {
      const int dl = (r & 3) + 8 * (r >> 2) + 4 * hi;
      ow[l31 * 72 + dl]      = f2b(Oa0[r] * inv);
      ow[l31 * 72 + 32 + dl] = f2b(Oa1[r] * inv);
    }
    __syncthreads();
#pragma unroll
    for (int it = 0; it < 4; ++it) {
      const int idx = it * 64 + lane;
      const int row = idx >> 3, blkk = idx & 7;
      bf16x8 v = *(const bf16x8*)(ow + row * 72 + blkk * 8);
      *(bf16x8*)(AO + (size_t)(b * S_ + qb + wave * 32 + row) * 2048 + h * 64 + blkk * 8) = v;
    }
  }
}

extern "C" void kernel_launch(void* const* d_in, const int* in_sizes, int n_in,
                              void* d_out, int out_size, void* d_ws, size_t ws_size,
                              hipStream_t stream) {
  (void)in_sizes; (void)n_in; (void)out_size; (void)ws_size;
  const float* x    = (const float*)d_in[0];
  const float* wq   = (const float*)d_in[1];
  const float* wk   = (const float*)d_in[2];
  const float* wv   = (const float*)d_in[3];
  const float* wo   = (const float*)d_in[4];
  const float* cosg = (const float*)d_in[5];
  const float* sing = (const float*)d_in[6];

  char* ws = (char*)d_ws;
  unsigned short* xb   = (unsigned short*)(ws);                 // 16,777,216
  unsigned short* wcat = (unsigned short*)(ws + 16777216);      // 12,582,912
  unsigned short* wob  = (unsigned short*)(ws + 29360128);      //  8,388,608
  float*          qkv  = (float*)         (ws + 37748736);      // 50,331,648
  unsigned short* Qb   = (unsigned short*)(ws + 88080384);      // 16,777,216
  unsigned short* Kb   = (unsigned short*)(ws + 104857600);     //  4,194,304
  unsigned short* Vtb  = (unsigned short*)(ws + 109051904);     //  4,194,304
  unsigned short* AO   = xb;

  f2bf_kernel<<<8192, 256, 0, stream>>>(x, xb, 2097152);
  wcat_kernel<<<6144, 256, 0, stream>>>(wq, wk, wv, wcat);
  f2bf_kernel<<<4096, 256, 0, stream>>>(wo, wob, 1048576);

  gemm_bt<<<dim3(NQKV / 128, MROWS / 128), 256, 0, stream>>>(xb, wcat, qkv, MROWS, NQKV, DM);

  rope_kernel<<<MROWS, 256, 0, stream>>>(qkv, cosg, sing, Qb, Kb, Vtb);

  attn_kernel<<<dim3(8, NH, B_), 256, 0, stream>>>(Qb, Kb, Vtb, AO);

  gemm_bt<<<dim3(DM / 128, MROWS / 128), 256, 0, stream>>>(AO, wob, (float*)d_out, MROWS, DM, DM);
}

// Round 5
// 226.657 us; speedup vs baseline: 1.7840x; 1.1300x over previous
//
#include <hip/hip_runtime.h>
#include <hip/hip_bf16.h>

#define B_   2
#define S_   2048
#define DM   2048
#define NH   32
#define NKV  8
#define HD   64
#define MROWS 4096   // B_*S_
#define NQKV  3072   // (NH+2*NKV)*HD

typedef __attribute__((ext_vector_type(8))) short bf16x8;
typedef __attribute__((ext_vector_type(4))) float f32x4;
typedef __attribute__((ext_vector_type(16))) float f32x16;

__device__ __forceinline__ unsigned short f2b(float f) {
  __hip_bfloat16 h = __float2bfloat16(f);
  return *reinterpret_cast<unsigned short*>(&h);
}

__device__ __forceinline__ void gload16(const void* g, void* l) {
  __builtin_amdgcn_global_load_lds((__attribute__((address_space(1))) void*)g,
                                   (__attribute__((address_space(3))) void*)l,
                                   16, 0, 0);
}

__device__ __forceinline__ unsigned cvtpk(float lo, float hi) {
  unsigned r;
  asm("v_cvt_pk_bf16_f32 %0, %1, %2" : "=v"(r) : "v"(lo), "v"(hi));
  return r;
}

__device__ __forceinline__ void pl32swap(unsigned& a, unsigned& b) {
  asm volatile("v_permlane32_swap_b32 %0, %1" : "+v"(a), "+v"(b));
}

__device__ __forceinline__ float exp2hw(float x) {   // 2^x via v_exp_f32
  float r;
  asm("v_exp_f32 %0, %1" : "=v"(r) : "v"(x));
  return r;
}

__device__ __forceinline__ bf16x8 mk8(unsigned w0, unsigned w1, unsigned w2, unsigned w3) {
  union { unsigned u[4]; bf16x8 v; } uu;
  uu.u[0] = w0; uu.u[1] = w1; uu.u[2] = w2; uu.u[3] = w3;
  return uu.v;
}

// ---------------- fp32 -> bf16 convert ----------------
__global__ __launch_bounds__(256) void f2bf_kernel(const float* __restrict__ in,
                                                   unsigned short* __restrict__ out, int n4) {
  int i = blockIdx.x * 256 + threadIdx.x;
  if (i < n4) {
    float4 v = reinterpret_cast<const float4*>(in)[i];
    ushort4 o;
    o.x = f2b(v.x); o.y = f2b(v.y); o.z = f2b(v.z); o.w = f2b(v.w);
    reinterpret_cast<ushort4*>(out)[i] = o;
  }
}

// ---------------- concat wq|wk|wv -> bf16 [3072][2048] ----------------
__global__ __launch_bounds__(256) void wcat_kernel(const float* __restrict__ wq,
                                                   const float* __restrict__ wk,
                                                   const float* __restrict__ wv,
                                                   unsigned short* __restrict__ out) {
  int i = blockIdx.x * 256 + threadIdx.x;
  int e = i * 4;
  int row = e >> 11;
  int col = e & 2047;
  const float* src;
  if (row < 2048)      src = wq + (size_t)row * 2048 + col;
  else if (row < 2560) src = wk + (size_t)(row - 2048) * 2048 + col;
  else                 src = wv + (size_t)(row - 2560) * 2048 + col;
  float4 v = *reinterpret_cast<const float4*>(src);
  ushort4 o;
  o.x = f2b(v.x); o.y = f2b(v.y); o.z = f2b(v.z); o.w = f2b(v.w);
  reinterpret_cast<ushort4*>(out)[i] = o;
}

// ---------------- GEMM C[M,N] = A[M,K] * B[N,K]^T  (bf16 in, fp32 out) ----------------
// Deep-pipelined: 256x128 tile, BK=64, 8 waves (4Mx2N), triple-buffered LDS (144KB),
// 2 phases/K-step, counted vmcnt(6) (T3+T4), T2 XOR-swizzle, T5 setprio.
#define BMg 256
#define BNg 128
#define BKg 64
__global__ __launch_bounds__(512, 2) void gemm_bt(const unsigned short* __restrict__ A,
                                                  const unsigned short* __restrict__ Bm,
                                                  float* __restrict__ C,
                                                  int M, int N, int K) {
  __shared__ unsigned short Abuf[3][BMg * BKg];   // 3 x 32KB
  __shared__ unsigned short Bbuf[3][BNg * BKg];   // 3 x 16KB
  const int tid = threadIdx.x;
  const int wave = tid >> 6, lane = tid & 63;
  const int wr = wave >> 1, wc = wave & 1;        // 4M x 2N wave grid
  const int rowbase = blockIdx.y * BMg;
  const int colbase = blockIdx.x * BNg;
  const unsigned short* Ag = A + (size_t)rowbase * K;
  const unsigned short* Bg = Bm + (size_t)colbase * K;
  const int NT = K / BKg;

  // stage one half-tile (2 A-chunks + 1 B-chunk per wave); LDS linear dest,
  // inverse-swizzled global source (rule 21): phys slot p holds logical col p^(r&7)
  auto stage_half = [&](int buf, int k0, int half) {
#pragma unroll
    for (int i = 0; i < 2; ++i) {
      int c = wave * 256 + (half * 2 + i) * 64 + lane;
      int r = c >> 3, p = c & 7;
      gload16(Ag + (size_t)r * K + k0 + ((p ^ (r & 7)) << 3),
              &Abuf[buf][(wave * 256 + (half * 2 + i) * 64) * 8]);
    }
    int c = wave * 128 + half * 64 + lane;
    int r = c >> 3, p = c & 7;
    gload16(Bg + (size_t)r * K + k0 + ((p ^ (r & 7)) << 3),
            &Bbuf[buf][(wave * 128 + half * 64) * 8]);
  };
  auto ldA = [&](int buf, int row, int c16) -> bf16x8 {
    return *(const bf16x8*)((const char*)&Abuf[buf][0] + row * 128 + ((c16 ^ (row & 7)) << 4));
  };
  auto ldB = [&](int buf, int row, int c16) -> bf16x8 {
    return *(const bf16x8*)((const char*)&Bbuf[buf][0] + row * 128 + ((c16 ^ (row & 7)) << 4));
  };

  f32x4 acc[4][4];
#pragma unroll
  for (int a = 0; a < 4; a++)
#pragma unroll
    for (int b2 = 0; b2 < 4; b2++) acc[a][b2] = (f32x4){0.f, 0.f, 0.f, 0.f};

  const int l15 = lane & 15, l4 = lane >> 4;

  // prologue: stage tiles 0 and 1 (12 loads); wait for tile 0 (oldest 6)
  stage_half(0, 0, 0); stage_half(0, 0, 1);
  stage_half(1, BKg, 0); stage_half(1, BKg, 1);
  asm volatile("s_waitcnt vmcnt(6)" ::: "memory");
  __builtin_amdgcn_s_barrier();

  int cur = 0;
  for (int t = 0; t < NT; ++t) {
    const int nxt2 = (cur >= 1) ? cur - 1 : cur + 2;   // (t+2)%3
    // ---- phase 1: ksub 0 ----
    {
      bf16x8 af[4], bfv[4];
#pragma unroll
      for (int mt = 0; mt < 4; ++mt) af[mt] = ldA(cur, wr * 64 + mt * 16 + l15, l4);
#pragma unroll
      for (int nt = 0; nt < 4; ++nt) bfv[nt] = ldB(cur, wc * 64 + nt * 16 + l15, l4);
      if (t + 2 < NT) stage_half(nxt2, (t + 2) * BKg, 0);
      __builtin_amdgcn_s_barrier();
      __builtin_amdgcn_s_setprio(1);
#pragma unroll
      for (int mt = 0; mt < 4; ++mt)
#pragma unroll
        for (int nt = 0; nt < 4; ++nt)
          acc[mt][nt] = __builtin_amdgcn_mfma_f32_16x16x32_bf16(af[mt], bfv[nt], acc[mt][nt], 0, 0, 0);
      __builtin_amdgcn_s_setprio(0);
      __builtin_amdgcn_s_barrier();
    }
    // ---- phase 2: ksub 1 ----
    {
      bf16x8 af[4], bfv[4];
#pragma unroll
      for (int mt = 0; mt < 4; ++mt) af[mt] = ldA(cur, wr * 64 + mt * 16 + l15, 4 + l4);
#pragma unroll
      for (int nt = 0; nt < 4; ++nt) bfv[nt] = ldB(cur, wc * 64 + nt * 16 + l15, 4 + l4);
      if (t + 2 < NT) stage_half(nxt2, (t + 2) * BKg, 1);
      __builtin_amdgcn_s_barrier();
      __builtin_amdgcn_s_setprio(1);
#pragma unroll
      for (int mt = 0; mt < 4; ++mt)
#pragma unroll
        for (int nt = 0; nt < 4; ++nt)
          acc[mt][nt] = __builtin_amdgcn_mfma_f32_16x16x32_bf16(af[mt], bfv[nt], acc[mt][nt], 0, 0, 0);
      __builtin_amdgcn_s_setprio(0);
      if (t < NT - 1) {
        if (t + 2 < NT) asm volatile("s_waitcnt vmcnt(6)" ::: "memory");   // counted: tile t+2 stays in flight
        else            asm volatile("s_waitcnt vmcnt(0)" ::: "memory");   // tail drain
        __builtin_amdgcn_s_barrier();
      }
    }
    cur = (cur < 2) ? cur + 1 : 0;
  }

  const int orow = rowbase + wr * 64, ocol = colbase + wc * 64;
#pragma unroll
  for (int mt = 0; mt < 4; mt++)
#pragma unroll
    for (int nt = 0; nt < 4; nt++)
#pragma unroll
      for (int r = 0; r < 4; r++)
        C[(size_t)(orow + mt * 16 + l4 * 4 + r) * N + ocol + nt * 16 + l15] = acc[mt][nt][r];
}

// ---------------- RoPE + layout: qkv fp32 -> Q/K/V^T bf16 ----------------
// Q is pre-scaled by 0.125*log2(e) so attention scores land in exp2 domain.
#define QSCALE 0.18033688011112042f
__global__ __launch_bounds__(256) void rope_kernel(const float* __restrict__ qkv,
                                                   const float* __restrict__ cosg,
                                                   const float* __restrict__ sing,
                                                   unsigned short* __restrict__ Qb,
                                                   unsigned short* __restrict__ Kb,
                                                   unsigned short* __restrict__ Vtb) {
  const int row = blockIdx.x;              // b*S + s
  const int b = row >> 11, s = row & 2047;
  __shared__ float cs[32], sn[32];
  if (threadIdx.x < 32) {
    cs[threadIdx.x] = cosg[s * 32 + threadIdx.x];
    sn[threadIdx.x] = sing[s * 32 + threadIdx.x];
  }
  __syncthreads();
  const float* qr = qkv + (size_t)row * NQKV;
  const int t = threadIdx.x;

  for (int pid = t; pid < 1024; pid += 256) {
    const int h = pid >> 5, i = pid & 31, i2 = i >> 1;
    float qa = qr[h * 64 + i], qb2 = qr[h * 64 + i + 32];
    size_t base = ((size_t)(b * NH + h) * S_ + s) * HD;
    Qb[base + i]      = f2b((qa * cs[i2] - qb2 * sn[i2]) * QSCALE);
    Qb[base + i + 32] = f2b((qb2 * cs[16 + i2] + qa * sn[16 + i2]) * QSCALE);
  }
  {
    const int h = t >> 5, i = t & 31, i2 = i >> 1;
    float ka = qr[2048 + h * 64 + i], kb2 = qr[2048 + h * 64 + i + 32];
    size_t base = ((size_t)(b * NKV + h) * S_ + s) * HD;
    Kb[base + i]      = f2b(ka * cs[i2] - kb2 * sn[i2]);
    Kb[base + i + 32] = f2b(kb2 * cs[16 + i2] + ka * sn[16 + i2]);
  }
  for (int j = t; j < 512; j += 256) {
    const int h = j >> 6, d = j & 63;
    Vtb[((size_t)(b * NKV + h) * HD + d) * S_ + s] = f2b(qr[2560 + j]);
  }
}

// ---------------- Flash attention: paired q-regions, 34 KV-tiles per block uniform ----------------
__device__ __forceinline__ void stage_kv(const unsigned short* __restrict__ Kbase,
                                         const unsigned short* __restrict__ Vbase,
                                         unsigned short* Kl, unsigned short* Vl,
                                         int j0, int wave, int lane) {
#pragma unroll
  for (int tt = 0; tt < 2; ++tt) {
    int slot = (wave * 2 + tt) * 64 + lane;
    int row = slot >> 3, blk = slot & 7;
    int sb = ((blk ^ (row & 7)) << 3);          // pre-swizzled global source (rule 21)
    gload16(Kbase + (size_t)(j0 + row) * HD + sb, Kl + (wave * 2 + tt) * 512);
    gload16(Vbase + (size_t)row * S_ + j0 + sb, Vl + (wave * 2 + tt) * 512);
  }
}

__global__ __launch_bounds__(256) void attn_kernel(const unsigned short* __restrict__ Q,
                                                   const unsigned short* __restrict__ Kg,
                                                   const unsigned short* __restrict__ Vt,
                                                   unsigned short* __restrict__ AO) {
  // paired q-regions: block pr handles qbi = 15-pr (long, first) then qbi = pr (short).
  const int pr = blockIdx.x, h = blockIdx.y, b = blockIdx.z;
  const int hk = h >> 2;
  __shared__ unsigned short kv_lds[16384];   // [2 buf][K 4KB] + [2 buf][V 4KB]
  __shared__ unsigned short ow_lds[9216];    // epilogue bounce [4 waves][32][72]
  const int tid = threadIdx.x, wave = tid >> 6, lane = tid & 63;
  const int l31 = lane & 31, hi = lane >> 5;

  const unsigned short* Qbase = Q + (size_t)(b * NH + h) * S_ * HD;
  const unsigned short* Kbase = Kg + (size_t)(b * NKV + hk) * S_ * HD;
  const unsigned short* Vbase = Vt + (size_t)(b * NKV + hk) * HD * S_;

  const int NT_B = 2 * (16 - pr);   // long region tile count
  const int NTtot = 34;

  stage_kv(Kbase, Vbase, kv_lds, kv_lds + 8192, 0, wave, lane);
  __syncthreads();
  int cur = 0;
  int tlin = 0;

  for (int rg = 0; rg < 2; ++rg) {
    const int qbi = rg == 0 ? (15 - pr) : pr;
    const int qb = qbi * 128;
    const int NT = 2 * (qbi + 1);
    const int q0w = qb + wave * 32;
    const int qg = q0w + l31;

    bf16x8 qf[4];
#pragma unroll
    for (int c = 0; c < 4; ++c)
      qf[c] = *reinterpret_cast<const bf16x8*>(Qbase + (size_t)qg * HD + c * 16 + hi * 8);

    f32x16 Oa0 = {}, Oa1 = {};
    float m_old = -INFINITY, lsum = 0.f;

    for (int t = 0; t < NT; ++t, ++tlin) {
      const int j0 = t * 64;
      const int tn = tlin + 1;
      if (tn < NTtot) {
        const int j0n = (tn < NT_B ? tn : tn - NT_B) * 64;
        stage_kv(Kbase, Vbase, kv_lds + (cur ^ 1) * 4096, kv_lds + 8192 + (cur ^ 1) * 4096,
                 j0n, wave, lane);
      }

      if (j0 < q0w + 32) {
        const char* Klc = (const char*)(kv_lds + cur * 4096);
        const char* Vlc = (const char*)(kv_lds + 8192 + cur * 4096);

        // S = K * Q  (lane owns q = qg; scores pre-scaled to exp2 domain)
        f32x16 s0 = {}, s1 = {};
        __builtin_amdgcn_s_setprio(1);
#pragma unroll
        for (int c = 0; c < 4; ++c) {
          const int r0 = l31;
          bf16x8 kf = *(const bf16x8*)(Klc + r0 * 128 + ((((c << 1) + hi) ^ (r0 & 7)) << 4));
          s0 = __builtin_amdgcn_mfma_f32_32x32x16_bf16(kf, qf[c], s0, 0, 0, 0);
        }
#pragma unroll
        for (int c = 0; c < 4; ++c) {
          const int r1 = 32 + l31;
          bf16x8 kf = *(const bf16x8*)(Klc + r1 * 128 + ((((c << 1) + hi) ^ (r1 & 7)) << 4));
          s1 = __builtin_amdgcn_mfma_f32_32x32x16_bf16(kf, qf[c], s1, 0, 0, 0);
        }
        __builtin_amdgcn_s_setprio(0);

        // causal mask (diagonal tiles only)
        const bool need_mask = (j0 + 63 > q0w);
        const int kb0 = j0 + 4 * hi, kb1 = j0 + 32 + 4 * hi;
        if (need_mask) {
#pragma unroll
          for (int r = 0; r < 16; ++r) {
            const int ko = (r & 3) + 8 * (r >> 2);
            if (kb0 + ko > qg) s0[r] = -INFINITY;
            if (kb1 + ko > qg) s1[r] = -INFINITY;
          }
        }

        // tree row-max (4 parallel chains)
        float a0 = fmaxf(s0[0], s1[0]), a1 = fmaxf(s0[1], s1[1]);
        float a2 = fmaxf(s0[2], s1[2]), a3 = fmaxf(s0[3], s1[3]);
#pragma unroll
        for (int r = 4; r < 16; r += 4) {
          a0 = fmaxf(a0, fmaxf(s0[r], s1[r]));
          a1 = fmaxf(a1, fmaxf(s0[r + 1], s1[r + 1]));
          a2 = fmaxf(a2, fmaxf(s0[r + 2], s1[r + 2]));
          a3 = fmaxf(a3, fmaxf(s0[r + 3], s1[r + 3]));
        }
        float mxt = fmaxf(fmaxf(a0, a1), fmaxf(a2, a3));
        mxt = fmaxf(mxt, __shfl_xor(mxt, 32, 64));

        // defer-rescale (T13)
        if (!__all(mxt - m_old <= 8.f)) {
          float mnew = fmaxf(m_old, mxt);
          float corr = exp2hw(m_old - mnew);
          m_old = mnew;
          lsum *= corr;
#pragma unroll
          for (int r = 0; r < 16; ++r) { Oa0[r] *= corr; Oa1[r] *= corr; }
        }

        // p = 2^(s - m); tree sum
        float t0 = 0.f, t1 = 0.f, t2 = 0.f, t3 = 0.f;
#pragma unroll
        for (int r = 0; r < 16; r += 4) {
          s0[r]     = exp2hw(s0[r] - m_old);     t0 += s0[r];
          s0[r + 1] = exp2hw(s0[r + 1] - m_old); t1 += s0[r + 1];
          s0[r + 2] = exp2hw(s0[r + 2] - m_old); t2 += s0[r + 2];
          s0[r + 3] = exp2hw(s0[r + 3] - m_old); t3 += s0[r + 3];
        }
#pragma unroll
        for (int r = 0; r < 16; r += 4) {
          s1[r]     = exp2hw(s1[r] - m_old);     t0 += s1[r];
          s1[r + 1] = exp2hw(s1[r + 1] - m_old); t1 += s1[r + 1];
          s1[r + 2] = exp2hw(s1[r + 2] - m_old); t2 += s1[r + 2];
          s1[r + 3] = exp2hw(s1[r + 3] - m_old); t3 += s1[r + 3];
        }
        float rs = (t0 + t1) + (t2 + t3);
        rs += __shfl_xor(rs, 32, 64);
        lsum += rs;

        // P -> bf16 B-fragments in-register
        unsigned a0u = cvtpk(s0[0], s0[1]),  b0u = cvtpk(s0[4], s0[5]);  pl32swap(a0u, b0u);
        unsigned a1u = cvtpk(s0[2], s0[3]),  b1u = cvtpk(s0[6], s0[7]);  pl32swap(a1u, b1u);
        bf16x8 pf00 = mk8(a0u, a1u, b0u, b1u);
        unsigned a2u = cvtpk(s0[8], s0[9]),  b2u = cvtpk(s0[12], s0[13]); pl32swap(a2u, b2u);
        unsigned a3u = cvtpk(s0[10], s0[11]), b3u = cvtpk(s0[14], s0[15]); pl32swap(a3u, b3u);
        bf16x8 pf01 = mk8(a2u, a3u, b2u, b3u);
        unsigned a4u = cvtpk(s1[0], s1[1]),  b4u = cvtpk(s1[4], s1[5]);  pl32swap(a4u, b4u);
        unsigned a5u = cvtpk(s1[2], s1[3]),  b5u = cvtpk(s1[6], s1[7]);  pl32swap(a5u, b5u);
        bf16x8 pf10 = mk8(a4u, a5u, b4u, b5u);
        unsigned a6u = cvtpk(s1[8], s1[9]),  b6u = cvtpk(s1[12], s1[13]); pl32swap(a6u, b6u);
        unsigned a7u = cvtpk(s1[10], s1[11]), b7u = cvtpk(s1[14], s1[15]); pl32swap(a7u, b7u);
        bf16x8 pf11 = mk8(a6u, a7u, b6u, b7u);

        // O^T += V^T * P
        __builtin_amdgcn_s_setprio(1);
#pragma unroll
        for (int sk = 0; sk < 4; ++sk) {
          const int s = sk >> 1, kc = sk & 1;
          const bf16x8 pf = (sk == 0) ? pf00 : (sk == 1) ? pf01 : (sk == 2) ? pf10 : pf11;
          {
            const int row = l31;
            bf16x8 vf = *(const bf16x8*)(Vlc + row * 128 +
                          ((((s << 2) + (kc << 1) + hi) ^ (row & 7)) << 4));
            Oa0 = __builtin_amdgcn_mfma_f32_32x32x16_bf16(vf, pf, Oa0, 0, 0, 0);
          }
          {
            const int row = 32 + l31;
            bf16x8 vf = *(const bf16x8*)(Vlc + row * 128 +
                          ((((s << 2) + (kc << 1) + hi) ^ (row & 7)) << 4));
            Oa1 = __builtin_amdgcn_mfma_f32_32x32x16_bf16(vf, pf, Oa1, 0, 0, 0);
          }
        }
        __builtin_amdgcn_s_setprio(0);
      }
      __syncthreads();
      cur ^= 1;
    }

    // epilogue: normalize, transpose via dedicated LDS bounce, coalesced write
    unsigned short* ow = ow_lds + wave * 2304;   // [32 q][72 d]
    const float inv = 1.0f / lsum;
#pragma unroll
    for (int r = 0; r < 16; ++r) {
      const int dl = (r & 3) + 8 * (r >> 2) + 4 * hi;
      ow[l31 * 72 + dl]      = f2b(Oa0[r] * inv);
      ow[l31 * 72 + 32 + dl] = f2b(Oa1[r] * inv);
    }
    __syncthreads();
#pragma unroll
    for (int it = 0; it < 4; ++it) {
      const int idx = it * 64 + lane;
      const int row = idx >> 3, blkk = idx & 7;
      bf16x8 v = *(const bf16x8*)(ow + row * 72 + blkk * 8);
      *(bf16x8*)(AO + (size_t)(b * S_ + qb + wave * 32 + row) * 2048 + h * 64 + blkk * 8) = v;
    }
  }
}

extern "C" void kernel_launch(void* const* d_in, const int* in_sizes, int n_in,
                              void* d_out, int out_size, void* d_ws, size_t ws_size,
                              hipStream_t stream) {
  (void)in_sizes; (void)n_in; (void)out_size; (void)ws_size;
  const float* x    = (const float*)d_in[0];
  const float* wq   = (const float*)d_in[1];
  const float* wk   = (const float*)d_in[2];
  const float* wv   = (const float*)d_in[3];
  const float* wo   = (const float*)d_in[4];
  const float* cosg = (const float*)d_in[5];
  const float* sing = (const float*)d_in[6];

  char* ws = (char*)d_ws;
  unsigned short* xb   = (unsigned short*)(ws);                 // 16,777,216
  unsigned short* wcat = (unsigned short*)(ws + 16777216);      // 12,582,912
  unsigned short* wob  = (unsigned short*)(ws + 29360128);      //  8,388,608
  float*          qkv  = (float*)         (ws + 37748736);      // 50,331,648
  unsigned short* Qb   = (unsigned short*)(ws + 88080384);      // 16,777,216
  unsigned short* Kb   = (unsigned short*)(ws + 104857600);     //  4,194,304
  unsigned short* Vtb  = (unsigned short*)(ws + 109051904);     //  4,194,304
  unsigned short* AO   = xb;

  f2bf_kernel<<<8192, 256, 0, stream>>>(x, xb, 2097152);
  wcat_kernel<<<6144, 256, 0, stream>>>(wq, wk, wv, wcat);
  f2bf_kernel<<<4096, 256, 0, stream>>>(wo, wob, 1048576);

  gemm_bt<<<dim3(NQKV / BNg, MROWS / BMg), 512, 0, stream>>>(xb, wcat, qkv, MROWS, NQKV, DM);

  rope_kernel<<<MROWS, 256, 0, stream>>>(qkv, cosg, sing, Qb, Kb, Vtb);

  attn_kernel<<<dim3(8, NH, B_), 256, 0, stream>>>(Qb, Kb, Vtb, AO);

  gemm_bt<<<dim3(DM / BNg, MROWS / BMg), 512, 0, stream>>>(AO, wob, (float*)d_out, MROWS, DM, DM);
}

// Round 6
// 203.634 us; speedup vs baseline: 1.9857x; 1.1131x over previous
//
#include <hip/hip_runtime.h>
#include <hip/hip_bf16.h>

#define B_   2
#define S_   2048
#define DM   2048
#define NH   32
#define NKV  8
#define HD   64
#define MROWS 4096   // B_*S_
#define NQKV  3072   // (NH+2*NKV)*HD

typedef __attribute__((ext_vector_type(8))) short bf16x8;
typedef __attribute__((ext_vector_type(4))) float f32x4;
typedef __attribute__((ext_vector_type(16))) float f32x16;

__device__ __forceinline__ unsigned short f2b(float f) {
  __hip_bfloat16 h = __float2bfloat16(f);
  return *reinterpret_cast<unsigned short*>(&h);
}

__device__ __forceinline__ void gload16(const void* g, void* l) {
  __builtin_amdgcn_global_load_lds((__attribute__((address_space(1))) void*)g,
                                   (__attribute__((address_space(3))) void*)l,
                                   16, 0, 0);
}

__device__ __forceinline__ unsigned cvtpk(float lo, float hi) {
  unsigned r;
  asm("v_cvt_pk_bf16_f32 %0, %1, %2" : "=v"(r) : "v"(lo), "v"(hi));
  return r;
}

__device__ __forceinline__ void pl32swap(unsigned& a, unsigned& b) {
  asm volatile("v_permlane32_swap_b32 %0, %1" : "+v"(a), "+v"(b));
}

__device__ __forceinline__ float exp2hw(float x) {   // 2^x via v_exp_f32
  float r;
  asm("v_exp_f32 %0, %1" : "=v"(r) : "v"(x));
  return r;
}

__device__ __forceinline__ bf16x8 mk8(unsigned w0, unsigned w1, unsigned w2, unsigned w3) {
  union { unsigned u[4]; bf16x8 v; } uu;
  uu.u[0] = w0; uu.u[1] = w1; uu.u[2] = w2; uu.u[3] = w3;
  return uu.v;
}

// ---------------- fp32 -> bf16 convert ----------------
__global__ __launch_bounds__(256) void f2bf_kernel(const float* __restrict__ in,
                                                   unsigned short* __restrict__ out, int n4) {
  int i = blockIdx.x * 256 + threadIdx.x;
  if (i < n4) {
    float4 v = reinterpret_cast<const float4*>(in)[i];
    ushort4 o;
    o.x = f2b(v.x); o.y = f2b(v.y); o.z = f2b(v.z); o.w = f2b(v.w);
    reinterpret_cast<ushort4*>(out)[i] = o;
  }
}

// ---------------- concat wq|wk|wv -> bf16 [3072][2048] ----------------
__global__ __launch_bounds__(256) void wcat_kernel(const float* __restrict__ wq,
                                                   const float* __restrict__ wk,
                                                   const float* __restrict__ wv,
                                                   unsigned short* __restrict__ out) {
  int i = blockIdx.x * 256 + threadIdx.x;
  int e = i * 4;
  int row = e >> 11;
  int col = e & 2047;
  const float* src;
  if (row < 2048)      src = wq + (size_t)row * 2048 + col;
  else if (row < 2560) src = wk + (size_t)(row - 2048) * 2048 + col;
  else                 src = wv + (size_t)(row - 2560) * 2048 + col;
  float4 v = *reinterpret_cast<const float4*>(src);
  ushort4 o;
  o.x = f2b(v.x); o.y = f2b(v.y); o.z = f2b(v.z); o.w = f2b(v.w);
  reinterpret_cast<ushort4*>(out)[i] = o;
}

#define BMg 256
#define BNg 128
#define BKg 64
#define QSCALE 0.18033688011112042f

// ---------------- fused QKV GEMM + RoPE + layout (bf16 out) ----------------
// Pipelined 256x128 tile as gemm_bt; epilogue: Q cols -> rope*QSCALE -> Qb[b,s][h*64+d],
// K cols -> rope -> Kb2[b,s][hk*64+d], V cols -> transpose -> Vtb[b,hk,d][s].
__global__ __launch_bounds__(512, 2) void gemm_qkv(const unsigned short* __restrict__ A,
                                                   const unsigned short* __restrict__ Bm,
                                                   unsigned short* __restrict__ Qb,
                                                   unsigned short* __restrict__ Kb2,
                                                   unsigned short* __restrict__ Vtb,
                                                   const float* __restrict__ cosg,
                                                   const float* __restrict__ sing) {
  const int K = DM;
  __shared__ unsigned short Abuf[3][BMg * BKg];
  __shared__ unsigned short Bbuf[3][BNg * BKg];
  const int tid = threadIdx.x;
  const int wave = tid >> 6, lane = tid & 63;
  const int wr = wave >> 1, wc = wave & 1;
  const int rowbase = blockIdx.y * BMg;
  const int colbase = blockIdx.x * BNg;
  const unsigned short* Ag = A + (size_t)rowbase * K;
  const unsigned short* Bg = Bm + (size_t)colbase * K;
  const int NT = K / BKg;

  auto stage_half = [&](int buf, int k0, int half) {
#pragma unroll
    for (int i = 0; i < 2; ++i) {
      int c = wave * 256 + (half * 2 + i) * 64 + lane;
      int r = c >> 3, p = c & 7;
      gload16(Ag + (size_t)r * K + k0 + ((p ^ (r & 7)) << 3),
              &Abuf[buf][(wave * 256 + (half * 2 + i) * 64) * 8]);
    }
    int c = wave * 128 + half * 64 + lane;
    int r = c >> 3, p = c & 7;
    gload16(Bg + (size_t)r * K + k0 + ((p ^ (r & 7)) << 3),
            &Bbuf[buf][(wave * 128 + half * 64) * 8]);
  };
  auto ldA = [&](int buf, int row, int c16) -> bf16x8 {
    return *(const bf16x8*)((const char*)&Abuf[buf][0] + row * 128 + ((c16 ^ (row & 7)) << 4));
  };
  auto ldB = [&](int buf, int row, int c16) -> bf16x8 {
    return *(const bf16x8*)((const char*)&Bbuf[buf][0] + row * 128 + ((c16 ^ (row & 7)) << 4));
  };

  f32x4 acc[4][4];
#pragma unroll
  for (int a = 0; a < 4; a++)
#pragma unroll
    for (int b2 = 0; b2 < 4; b2++) acc[a][b2] = (f32x4){0.f, 0.f, 0.f, 0.f};

  const int l15 = lane & 15, l4 = lane >> 4;

  stage_half(0, 0, 0); stage_half(0, 0, 1);
  stage_half(1, BKg, 0); stage_half(1, BKg, 1);
  asm volatile("s_waitcnt vmcnt(6)" ::: "memory");
  __builtin_amdgcn_s_barrier();

  int cur = 0;
  for (int t = 0; t < NT; ++t) {
    const int nxt2 = (cur >= 1) ? cur - 1 : cur + 2;
    {
      bf16x8 af[4], bfv[4];
#pragma unroll
      for (int mt = 0; mt < 4; ++mt) af[mt] = ldA(cur, wr * 64 + mt * 16 + l15, l4);
#pragma unroll
      for (int nt = 0; nt < 4; ++nt) bfv[nt] = ldB(cur, wc * 64 + nt * 16 + l15, l4);
      if (t + 2 < NT) stage_half(nxt2, (t + 2) * BKg, 0);
      __builtin_amdgcn_s_barrier();
      __builtin_amdgcn_s_setprio(1);
#pragma unroll
      for (int mt = 0; mt < 4; ++mt)
#pragma unroll
        for (int nt = 0; nt < 4; ++nt)
          acc[mt][nt] = __builtin_amdgcn_mfma_f32_16x16x32_bf16(af[mt], bfv[nt], acc[mt][nt], 0, 0, 0);
      __builtin_amdgcn_s_setprio(0);
      __builtin_amdgcn_s_barrier();
    }
    {
      bf16x8 af[4], bfv[4];
#pragma unroll
      for (int mt = 0; mt < 4; ++mt) af[mt] = ldA(cur, wr * 64 + mt * 16 + l15, 4 + l4);
#pragma unroll
      for (int nt = 0; nt < 4; ++nt) bfv[nt] = ldB(cur, wc * 64 + nt * 16 + l15, 4 + l4);
      if (t + 2 < NT) stage_half(nxt2, (t + 2) * BKg, 1);
      __builtin_amdgcn_s_barrier();
      __builtin_amdgcn_s_setprio(1);
#pragma unroll
      for (int mt = 0; mt < 4; ++mt)
#pragma unroll
        for (int nt = 0; nt < 4; ++nt)
          acc[mt][nt] = __builtin_amdgcn_mfma_f32_16x16x32_bf16(af[mt], bfv[nt], acc[mt][nt], 0, 0, 0);
      __builtin_amdgcn_s_setprio(0);
      if (t < NT - 1) {
        if (t + 2 < NT) asm volatile("s_waitcnt vmcnt(6)" ::: "memory");
        else            asm volatile("s_waitcnt vmcnt(0)" ::: "memory");
        __builtin_amdgcn_s_barrier();
      }
    }
    cur = (cur < 2) ? cur + 1 : 0;
  }

  const int orow = rowbase + wr * 64, ocol = colbase + wc * 64;
  if (colbase < 2048) {
    // ---- Q: rope + QSCALE -> Qb[row][h*64+d] ----
#pragma unroll
    for (int mt = 0; mt < 4; ++mt)
#pragma unroll
      for (int r = 0; r < 4; ++r) {
        const int row = orow + mt * 16 + l4 * 4 + r;
        const int s = row & 2047;
        const float* cR = cosg + s * 32;
        const float* sR = sing + s * 32;
#pragma unroll
        for (int nt = 0; nt < 2; ++nt) {
          const int i2 = nt * 8 + (l15 >> 1);
          float c0 = cR[i2], sv0 = sR[i2], c1 = cR[16 + i2], sv1 = sR[16 + i2];
          float alo = acc[mt][nt][r], ahi = acc[mt][nt + 2][r];
          size_t base = (size_t)row * 2048 + ocol + nt * 16 + l15;
          Qb[base]      = f2b((alo * c0 - ahi * sv0) * QSCALE);
          Qb[base + 32] = f2b((ahi * c1 + alo * sv1) * QSCALE);
        }
      }
  } else if (colbase < 2560) {
    // ---- K: rope -> Kb2[row][hk*64+d] ----
    const int kcol = ocol - 2048;
#pragma unroll
    for (int mt = 0; mt < 4; ++mt)
#pragma unroll
      for (int r = 0; r < 4; ++r) {
        const int row = orow + mt * 16 + l4 * 4 + r;
        const int s = row & 2047;
        const float* cR = cosg + s * 32;
        const float* sR = sing + s * 32;
#pragma unroll
        for (int nt = 0; nt < 2; ++nt) {
          const int i2 = nt * 8 + (l15 >> 1);
          float c0 = cR[i2], sv0 = sR[i2], c1 = cR[16 + i2], sv1 = sR[16 + i2];
          float alo = acc[mt][nt][r], ahi = acc[mt][nt + 2][r];
          size_t base = (size_t)row * 512 + kcol + nt * 16 + l15;
          Kb2[base]      = f2b(alo * c0 - ahi * sv0);
          Kb2[base + 32] = f2b(ahi * c1 + alo * sv1);
        }
      }
  } else {
    // ---- V: transpose -> Vtb[b,hk,d][s] ----
    const int hkv = (ocol - 2560) >> 6;
#pragma unroll
    for (int mt = 0; mt < 4; ++mt)
#pragma unroll
      for (int nt = 0; nt < 4; ++nt) {
        const int d = nt * 16 + l15;
        const int row0 = orow + mt * 16 + l4 * 4;
        const int b = row0 >> 11, s0i = row0 & 2047;
        ushort4 u;
        u.x = f2b(acc[mt][nt][0]); u.y = f2b(acc[mt][nt][1]);
        u.z = f2b(acc[mt][nt][2]); u.w = f2b(acc[mt][nt][3]);
        *(ushort4*)(Vtb + ((size_t)(b * NKV + hkv) * HD + d) * S_ + s0i) = u;
      }
  }
}

// ---------------- GEMM C[M,N] = A[M,K] * B[N,K]^T  (bf16 in, fp32 out) ----------------
__global__ __launch_bounds__(512, 2) void gemm_bt(const unsigned short* __restrict__ A,
                                                  const unsigned short* __restrict__ Bm,
                                                  float* __restrict__ C,
                                                  int M, int N, int K) {
  __shared__ unsigned short Abuf[3][BMg * BKg];
  __shared__ unsigned short Bbuf[3][BNg * BKg];
  const int tid = threadIdx.x;
  const int wave = tid >> 6, lane = tid & 63;
  const int wr = wave >> 1, wc = wave & 1;
  const int rowbase = blockIdx.y * BMg;
  const int colbase = blockIdx.x * BNg;
  const unsigned short* Ag = A + (size_t)rowbase * K;
  const unsigned short* Bg = Bm + (size_t)colbase * K;
  const int NT = K / BKg;

  auto stage_half = [&](int buf, int k0, int half) {
#pragma unroll
    for (int i = 0; i < 2; ++i) {
      int c = wave * 256 + (half * 2 + i) * 64 + lane;
      int r = c >> 3, p = c & 7;
      gload16(Ag + (size_t)r * K + k0 + ((p ^ (r & 7)) << 3),
              &Abuf[buf][(wave * 256 + (half * 2 + i) * 64) * 8]);
    }
    int c = wave * 128 + half * 64 + lane;
    int r = c >> 3, p = c & 7;
    gload16(Bg + (size_t)r * K + k0 + ((p ^ (r & 7)) << 3),
            &Bbuf[buf][(wave * 128 + half * 64) * 8]);
  };
  auto ldA = [&](int buf, int row, int c16) -> bf16x8 {
    return *(const bf16x8*)((const char*)&Abuf[buf][0] + row * 128 + ((c16 ^ (row & 7)) << 4));
  };
  auto ldB = [&](int buf, int row, int c16) -> bf16x8 {
    return *(const bf16x8*)((const char*)&Bbuf[buf][0] + row * 128 + ((c16 ^ (row & 7)) << 4));
  };

  f32x4 acc[4][4];
#pragma unroll
  for (int a = 0; a < 4; a++)
#pragma unroll
    for (int b2 = 0; b2 < 4; b2++) acc[a][b2] = (f32x4){0.f, 0.f, 0.f, 0.f};

  const int l15 = lane & 15, l4 = lane >> 4;

  stage_half(0, 0, 0); stage_half(0, 0, 1);
  stage_half(1, BKg, 0); stage_half(1, BKg, 1);
  asm volatile("s_waitcnt vmcnt(6)" ::: "memory");
  __builtin_amdgcn_s_barrier();

  int cur = 0;
  for (int t = 0; t < NT; ++t) {
    const int nxt2 = (cur >= 1) ? cur - 1 : cur + 2;
    {
      bf16x8 af[4], bfv[4];
#pragma unroll
      for (int mt = 0; mt < 4; ++mt) af[mt] = ldA(cur, wr * 64 + mt * 16 + l15, l4);
#pragma unroll
      for (int nt = 0; nt < 4; ++nt) bfv[nt] = ldB(cur, wc * 64 + nt * 16 + l15, l4);
      if (t + 2 < NT) stage_half(nxt2, (t + 2) * BKg, 0);
      __builtin_amdgcn_s_barrier();
      __builtin_amdgcn_s_setprio(1);
#pragma unroll
      for (int mt = 0; mt < 4; ++mt)
#pragma unroll
        for (int nt = 0; nt < 4; ++nt)
          acc[mt][nt] = __builtin_amdgcn_mfma_f32_16x16x32_bf16(af[mt], bfv[nt], acc[mt][nt], 0, 0, 0);
      __builtin_amdgcn_s_setprio(0);
      __builtin_amdgcn_s_barrier();
    }
    {
      bf16x8 af[4], bfv[4];
#pragma unroll
      for (int mt = 0; mt < 4; ++mt) af[mt] = ldA(cur, wr * 64 + mt * 16 + l15, 4 + l4);
#pragma unroll
      for (int nt = 0; nt < 4; ++nt) bfv[nt] = ldB(cur, wc * 64 + nt * 16 + l15, 4 + l4);
      if (t + 2 < NT) stage_half(nxt2, (t + 2) * BKg, 1);
      __builtin_amdgcn_s_barrier();
      __builtin_amdgcn_s_setprio(1);
#pragma unroll
      for (int mt = 0; mt < 4; ++mt)
#pragma unroll
        for (int nt = 0; nt < 4; ++nt)
          acc[mt][nt] = __builtin_amdgcn_mfma_f32_16x16x32_bf16(af[mt], bfv[nt], acc[mt][nt], 0, 0, 0);
      __builtin_amdgcn_s_setprio(0);
      if (t < NT - 1) {
        if (t + 2 < NT) asm volatile("s_waitcnt vmcnt(6)" ::: "memory");
        else            asm volatile("s_waitcnt vmcnt(0)" ::: "memory");
        __builtin_amdgcn_s_barrier();
      }
    }
    cur = (cur < 2) ? cur + 1 : 0;
  }

  const int orow = rowbase + wr * 64, ocol = colbase + wc * 64;
#pragma unroll
  for (int mt = 0; mt < 4; mt++)
#pragma unroll
    for (int nt = 0; nt < 4; nt++)
#pragma unroll
      for (int r = 0; r < 4; r++)
        C[(size_t)(orow + mt * 16 + l4 * 4 + r) * N + ocol + nt * 16 + l15] = acc[mt][nt][r];
}

// ---------------- Flash attention: paired q-regions, 3-buffer ring, counted vmcnt ----------------
__global__ __launch_bounds__(256) void attn_kernel(const unsigned short* __restrict__ Qb,
                                                   const unsigned short* __restrict__ Kb2,
                                                   const unsigned short* __restrict__ Vt,
                                                   unsigned short* __restrict__ AO) {
  // paired q-regions: block pr handles qbi = 15-pr (long) then qbi = pr (short); 34 tiles uniform.
  const int pr = blockIdx.x, h = blockIdx.y, b = blockIdx.z;
  const int hk = h >> 2;
  __shared__ unsigned short Kbuf[3][4096];   // 3 x 8KB
  __shared__ unsigned short Vbuf[3][4096];   // 3 x 8KB
  const int tid = threadIdx.x, wave = tid >> 6, lane = tid & 63;
  const int l31 = lane & 31, hi = lane >> 5;

  const unsigned short* Qrow = Qb + (size_t)b * S_ * 2048 + h * 64;
  const unsigned short* Krow = Kb2 + (size_t)b * S_ * 512 + hk * 64;
  const unsigned short* Vbase = Vt + (size_t)(b * NKV + hk) * HD * S_;

  const int NT_B = 2 * (16 - pr);
  const int NTtot = 34;

  auto j0_of = [&](int tl) { return (tl < NT_B ? tl : tl - NT_B) * 64; };
  auto stage = [&](int j0, int bufi) {
#pragma unroll
    for (int tt = 0; tt < 2; ++tt) {
      int slot = (wave * 2 + tt) * 64 + lane;
      int row = slot >> 3, blk = slot & 7;
      int sb = ((blk ^ (row & 7)) << 3);          // pre-swizzled global source
      gload16(Krow + (size_t)(j0 + row) * 512 + sb, &Kbuf[bufi][(wave * 2 + tt) * 512]);
      gload16(Vbase + (size_t)row * S_ + j0 + sb, &Vbuf[bufi][(wave * 2 + tt) * 512]);
    }
  };

  stage(0, 0);
  stage(j0_of(1), 1);
  asm volatile("s_waitcnt vmcnt(4)" ::: "memory");
  __builtin_amdgcn_s_barrier();

  int cur = 0, tlin = 0;

  for (int rg = 0; rg < 2; ++rg) {
    const int qbi = rg == 0 ? (15 - pr) : pr;
    const int qb = qbi * 128;
    const int NT = 2 * (qbi + 1);
    const int q0w = qb + wave * 32;
    const int qg = q0w + l31;

    bf16x8 qf[4];
#pragma unroll
    for (int c = 0; c < 4; ++c)
      qf[c] = *reinterpret_cast<const bf16x8*>(Qrow + (size_t)qg * 2048 + c * 16 + hi * 8);

    f32x16 Oa0 = {}, Oa1 = {};
    float m_old = -INFINITY, lsum = 0.f;

    for (int t = 0; t < NT; ++t, ++tlin) {
      const int j0 = t * 64;
      if (tlin + 2 < NTtot) stage(j0_of(tlin + 2), cur >= 1 ? cur - 1 : cur + 2);

      if (j0 < q0w + 32) {
        const char* Klc = (const char*)&Kbuf[cur][0];
        const char* Vlc = (const char*)&Vbuf[cur][0];

        f32x16 s0 = {}, s1 = {};
        __builtin_amdgcn_s_setprio(1);
#pragma unroll
        for (int c = 0; c < 4; ++c) {
          const int r0 = l31;
          bf16x8 kf = *(const bf16x8*)(Klc + r0 * 128 + ((((c << 1) + hi) ^ (r0 & 7)) << 4));
          s0 = __builtin_amdgcn_mfma_f32_32x32x16_bf16(kf, qf[c], s0, 0, 0, 0);
        }
#pragma unroll
        for (int c = 0; c < 4; ++c) {
          const int r1 = 32 + l31;
          bf16x8 kf = *(const bf16x8*)(Klc + r1 * 128 + ((((c << 1) + hi) ^ (r1 & 7)) << 4));
          s1 = __builtin_amdgcn_mfma_f32_32x32x16_bf16(kf, qf[c], s1, 0, 0, 0);
        }
        __builtin_amdgcn_s_setprio(0);

        const bool need_mask = (j0 + 63 > q0w);
        const int kb0 = j0 + 4 * hi, kb1 = j0 + 32 + 4 * hi;
        if (need_mask) {
#pragma unroll
          for (int r = 0; r < 16; ++r) {
            const int ko = (r & 3) + 8 * (r >> 2);
            if (kb0 + ko > qg) s0[r] = -INFINITY;
            if (kb1 + ko > qg) s1[r] = -INFINITY;
          }
        }

        float a0 = fmaxf(s0[0], s1[0]), a1 = fmaxf(s0[1], s1[1]);
        float a2 = fmaxf(s0[2], s1[2]), a3 = fmaxf(s0[3], s1[3]);
#pragma unroll
        for (int r = 4; r < 16; r += 4) {
          a0 = fmaxf(a0, fmaxf(s0[r], s1[r]));
          a1 = fmaxf(a1, fmaxf(s0[r + 1], s1[r + 1]));
          a2 = fmaxf(a2, fmaxf(s0[r + 2], s1[r + 2]));
          a3 = fmaxf(a3, fmaxf(s0[r + 3], s1[r + 3]));
        }
        float mxt = fmaxf(fmaxf(a0, a1), fmaxf(a2, a3));
        mxt = fmaxf(mxt, __shfl_xor(mxt, 32, 64));

        if (!__all(mxt - m_old <= 8.f)) {
          float mnew = fmaxf(m_old, mxt);
          float corr = exp2hw(m_old - mnew);
          m_old = mnew;
          lsum *= corr;
#pragma unroll
          for (int r = 0; r < 16; ++r) { Oa0[r] *= corr; Oa1[r] *= corr; }
        }

        float t0 = 0.f, t1 = 0.f, t2 = 0.f, t3 = 0.f;
#pragma unroll
        for (int r = 0; r < 16; r += 4) {
          s0[r]     = exp2hw(s0[r] - m_old);     t0 += s0[r];
          s0[r + 1] = exp2hw(s0[r + 1] - m_old); t1 += s0[r + 1];
          s0[r + 2] = exp2hw(s0[r + 2] - m_old); t2 += s0[r + 2];
          s0[r + 3] = exp2hw(s0[r + 3] - m_old); t3 += s0[r + 3];
        }
#pragma unroll
        for (int r = 0; r < 16; r += 4) {
          s1[r]     = exp2hw(s1[r] - m_old);     t0 += s1[r];
          s1[r + 1] = exp2hw(s1[r + 1] - m_old); t1 += s1[r + 1];
          s1[r + 2] = exp2hw(s1[r + 2] - m_old); t2 += s1[r + 2];
          s1[r + 3] = exp2hw(s1[r + 3] - m_old); t3 += s1[r + 3];
        }
        float rs = (t0 + t1) + (t2 + t3);
        rs += __shfl_xor(rs, 32, 64);
        lsum += rs;

        unsigned a0u = cvtpk(s0[0], s0[1]),  b0u = cvtpk(s0[4], s0[5]);  pl32swap(a0u, b0u);
        unsigned a1u = cvtpk(s0[2], s0[3]),  b1u = cvtpk(s0[6], s0[7]);  pl32swap(a1u, b1u);
        bf16x8 pf00 = mk8(a0u, a1u, b0u, b1u);
        unsigned a2u = cvtpk(s0[8], s0[9]),  b2u = cvtpk(s0[12], s0[13]); pl32swap(a2u, b2u);
        unsigned a3u = cvtpk(s0[10], s0[11]), b3u = cvtpk(s0[14], s0[15]); pl32swap(a3u, b3u);
        bf16x8 pf01 = mk8(a2u, a3u, b2u, b3u);
        unsigned a4u = cvtpk(s1[0], s1[1]),  b4u = cvtpk(s1[4], s1[5]);  pl32swap(a4u, b4u);
        unsigned a5u = cvtpk(s1[2], s1[3]),  b5u = cvtpk(s1[6], s1[7]);  pl32swap(a5u, b5u);
        bf16x8 pf10 = mk8(a4u, a5u, b4u, b5u);
        unsigned a6u = cvtpk(s1[8], s1[9]),  b6u = cvtpk(s1[12], s1[13]); pl32swap(a6u, b6u);
        unsigned a7u = cvtpk(s1[10], s1[11]), b7u = cvtpk(s1[14], s1[15]); pl32swap(a7u, b7u);
        bf16x8 pf11 = mk8(a6u, a7u, b6u, b7u);

        __builtin_amdgcn_s_setprio(1);
#pragma unroll
        for (int sk = 0; sk < 4; ++sk) {
          const int s = sk >> 1, kc = sk & 1;
          const bf16x8 pf = (sk == 0) ? pf00 : (sk == 1) ? pf01 : (sk == 2) ? pf10 : pf11;
          {
            const int row = l31;
            bf16x8 vf = *(const bf16x8*)(Vlc + row * 128 +
                          ((((s << 2) + (kc << 1) + hi) ^ (row & 7)) << 4));
            Oa0 = __builtin_amdgcn_mfma_f32_32x32x16_bf16(vf, pf, Oa0, 0, 0, 0);
          }
          {
            const int row = 32 + l31;
            bf16x8 vf = *(const bf16x8*)(Vlc + row * 128 +
                          ((((s << 2) + (kc << 1) + hi) ^ (row & 7)) << 4));
            Oa1 = __builtin_amdgcn_mfma_f32_32x32x16_bf16(vf, pf, Oa1, 0, 0, 0);
          }
        }
        __builtin_amdgcn_s_setprio(0);
      }

      if (tlin + 1 < NTtot) {
        if (tlin + 2 < NTtot) asm volatile("s_waitcnt vmcnt(4)" ::: "memory");
        else                  asm volatile("s_waitcnt vmcnt(0)" ::: "memory");
        __builtin_amdgcn_s_barrier();
      }
      cur = (cur < 2) ? cur + 1 : 0;
    }

    // epilogue: normalize, direct global stores (ushort4 chunks; L2 merges lines)
    const float inv = 1.0f / lsum;
    unsigned short* ob = AO + (size_t)(b * S_ + qg) * 2048 + h * 64;
#pragma unroll
    for (int c = 0; c < 4; ++c) {
      ushort4 u0, u1;
      u0.x = f2b(Oa0[4 * c] * inv);     u0.y = f2b(Oa0[4 * c + 1] * inv);
      u0.z = f2b(Oa0[4 * c + 2] * inv); u0.w = f2b(Oa0[4 * c + 3] * inv);
      u1.x = f2b(Oa1[4 * c] * inv);     u1.y = f2b(Oa1[4 * c + 1] * inv);
      u1.z = f2b(Oa1[4 * c + 2] * inv); u1.w = f2b(Oa1[4 * c + 3] * inv);
      *(ushort4*)(ob + 8 * c + 4 * hi)      = u0;
      *(ushort4*)(ob + 32 + 8 * c + 4 * hi) = u1;
    }
  }
}

extern "C" void kernel_launch(void* const* d_in, const int* in_sizes, int n_in,
                              void* d_out, int out_size, void* d_ws, size_t ws_size,
                              hipStream_t stream) {
  (void)in_sizes; (void)n_in; (void)out_size; (void)ws_size;
  const float* x    = (const float*)d_in[0];
  const float* wq   = (const float*)d_in[1];
  const float* wk   = (const float*)d_in[2];
  const float* wv   = (const float*)d_in[3];
  const float* wo   = (const float*)d_in[4];
  const float* wo_  = wo;
  const float* cosg = (const float*)d_in[5];
  const float* sing = (const float*)d_in[6];
  (void)wo_;

  char* ws = (char*)d_ws;
  unsigned short* xb   = (unsigned short*)(ws);                 // 16,777,216 (reused as AO)
  unsigned short* wcat = (unsigned short*)(ws + 16777216);      // 12,582,912
  unsigned short* wob  = (unsigned short*)(ws + 29360128);      //  8,388,608
  unsigned short* Qb   = (unsigned short*)(ws + 37748736);      // 16,777,216
  unsigned short* Kb2  = (unsigned short*)(ws + 54525952);      //  4,194,304
  unsigned short* Vtb  = (unsigned short*)(ws + 58720256);      //  4,194,304
  unsigned short* AO   = xb;

  f2bf_kernel<<<8192, 256, 0, stream>>>(x, xb, 2097152);
  wcat_kernel<<<6144, 256, 0, stream>>>(wq, wk, wv, wcat);
  f2bf_kernel<<<4096, 256, 0, stream>>>(wo, wob, 1048576);

  gemm_qkv<<<dim3(NQKV / BNg, MROWS / BMg), 512, 0, stream>>>(xb, wcat, Qb, Kb2, Vtb, cosg, sing);

  attn_kernel<<<dim3(8, NH, B_), 256, 0, stream>>>(Qb, Kb2, Vtb, AO);

  gemm_bt<<<dim3(DM / BNg, MROWS / BMg), 512, 0, stream>>>(AO, wob, (float*)d_out, MROWS, DM, DM);
}

// Round 7
// 184.323 us; speedup vs baseline: 2.1937x; 1.1048x over previous
//
#include <hip/hip_runtime.h>
#include <hip/hip_bf16.h>

#define B_   2
#define S_   2048
#define DM   2048
#define NH   32
#define NKV  8
#define HD   64
#define MROWS 4096   // B_*S_
#define NQKV  3072   // (NH+2*NKV)*HD

typedef __attribute__((ext_vector_type(8))) short bf16x8;
typedef __attribute__((ext_vector_type(4))) float f32x4;
typedef __attribute__((ext_vector_type(16))) float f32x16;

__device__ __forceinline__ unsigned short f2b(float f) {
  __hip_bfloat16 h = __float2bfloat16(f);
  return *reinterpret_cast<unsigned short*>(&h);
}

__device__ __forceinline__ void gload16(const void* g, void* l) {
  __builtin_amdgcn_global_load_lds((__attribute__((address_space(1))) void*)g,
                                   (__attribute__((address_space(3))) void*)l,
                                   16, 0, 0);
}

__device__ __forceinline__ unsigned cvtpk(float lo, float hi) {
  unsigned r;
  asm("v_cvt_pk_bf16_f32 %0, %1, %2" : "=v"(r) : "v"(lo), "v"(hi));
  return r;
}

__device__ __forceinline__ void pl32swap(unsigned& a, unsigned& b) {
  asm volatile("v_permlane32_swap_b32 %0, %1" : "+v"(a), "+v"(b));
}

__device__ __forceinline__ float exp2hw(float x) {   // 2^x via v_exp_f32
  float r;
  asm("v_exp_f32 %0, %1" : "=v"(r) : "v"(x));
  return r;
}

__device__ __forceinline__ bf16x8 mk8(unsigned w0, unsigned w1, unsigned w2, unsigned w3) {
  union { unsigned u[4]; bf16x8 v; } uu;
  uu.u[0] = w0; uu.u[1] = w1; uu.u[2] = w2; uu.u[3] = w3;
  return uu.v;
}

// ---------------- fp32 -> bf16 convert ----------------
__global__ __launch_bounds__(256) void f2bf_kernel(const float* __restrict__ in,
                                                   unsigned short* __restrict__ out, int n4) {
  int i = blockIdx.x * 256 + threadIdx.x;
  if (i < n4) {
    float4 v = reinterpret_cast<const float4*>(in)[i];
    ushort4 o;
    o.x = f2b(v.x); o.y = f2b(v.y); o.z = f2b(v.z); o.w = f2b(v.w);
    reinterpret_cast<ushort4*>(out)[i] = o;
  }
}

// ---------------- concat wq|wk|wv -> bf16 [3072][2048] ----------------
__global__ __launch_bounds__(256) void wcat_kernel(const float* __restrict__ wq,
                                                   const float* __restrict__ wk,
                                                   const float* __restrict__ wv,
                                                   unsigned short* __restrict__ out) {
  int i = blockIdx.x * 256 + threadIdx.x;
  int e = i * 4;
  int row = e >> 11;
  int col = e & 2047;
  const float* src;
  if (row < 2048)      src = wq + (size_t)row * 2048 + col;
  else if (row < 2560) src = wk + (size_t)(row - 2048) * 2048 + col;
  else                 src = wv + (size_t)(row - 2560) * 2048 + col;
  float4 v = *reinterpret_cast<const float4*>(src);
  ushort4 o;
  o.x = f2b(v.x); o.y = f2b(v.y); o.z = f2b(v.z); o.w = f2b(v.w);
  reinterpret_cast<ushort4*>(out)[i] = o;
}

#define QSCALE 0.18033688011112042f

// ---------------- fused QKV GEMM + RoPE + layout (bf16 out) ----------------
// 128x128 tile, BK=32, 3-buffer ring, 48KB LDS -> 3 blocks/CU; grid 768 = exactly 3/CU.
__global__ __launch_bounds__(256, 3) void gemm_qkv(const unsigned short* __restrict__ A,
                                                   const unsigned short* __restrict__ Bm,
                                                   unsigned short* __restrict__ Qb,
                                                   unsigned short* __restrict__ Kb2,
                                                   unsigned short* __restrict__ Vtb,
                                                   const float* __restrict__ cosg,
                                                   const float* __restrict__ sing) {
  const int K = DM;
  __shared__ unsigned short Abuf[3][128 * 32];   // 3 x 8KB
  __shared__ unsigned short Bbuf[3][128 * 32];   // 3 x 8KB
  const int tid = threadIdx.x;
  const int wave = tid >> 6, lane = tid & 63;
  const int wr = wave >> 1, wc = wave & 1;       // 2x2 wave grid, 64x64 each
  const int rowbase = blockIdx.y * 128;
  const int colbase = blockIdx.x * 128;
  const unsigned short* Ag = A + (size_t)rowbase * K;
  const unsigned short* Bg = Bm + (size_t)colbase * K;
  const int NT = K / 32;                         // 64 steps

  // swizzle g(row) = (row>>1)&3 on 16B chunks of 64B rows (2-way bank alias = free)
  auto stage = [&](int buf, int k0) {
#pragma unroll
    for (int it = 0; it < 2; ++it) {
      int slot = wave * 128 + it * 64 + lane;
      int r = slot >> 2, p = slot & 3;
      gload16(Ag + (size_t)r * K + k0 + ((p ^ ((r >> 1) & 3)) << 3),
              &Abuf[buf][(wave * 128 + it * 64) * 8]);
    }
#pragma unroll
    for (int it = 0; it < 2; ++it) {
      int slot = wave * 128 + it * 64 + lane;
      int r = slot >> 2, p = slot & 3;
      gload16(Bg + (size_t)r * K + k0 + ((p ^ ((r >> 1) & 3)) << 3),
              &Bbuf[buf][(wave * 128 + it * 64) * 8]);
    }
  };
  auto ldA = [&](int buf, int row, int c) -> bf16x8 {
    return *(const bf16x8*)((const char*)&Abuf[buf][0] + row * 64 + ((c ^ ((row >> 1) & 3)) << 4));
  };
  auto ldB = [&](int buf, int row, int c) -> bf16x8 {
    return *(const bf16x8*)((const char*)&Bbuf[buf][0] + row * 64 + ((c ^ ((row >> 1) & 3)) << 4));
  };

  f32x4 acc[4][4];
#pragma unroll
  for (int a = 0; a < 4; a++)
#pragma unroll
    for (int b2 = 0; b2 < 4; b2++) acc[a][b2] = (f32x4){0.f, 0.f, 0.f, 0.f};

  const int l15 = lane & 15, l4 = lane >> 4;

  // prologue: stage steps 0,1 (4 loads/lane each); wait step 0 (oldest 4)
  stage(0, 0);
  stage(1, 32);
  asm volatile("s_waitcnt vmcnt(4)" ::: "memory");
  __builtin_amdgcn_s_barrier();

  int cur = 0;
  for (int t = 0; t < NT; ++t) {
    const int nxt2 = (cur >= 1) ? cur - 1 : cur + 2;   // (t+2)%3
    bf16x8 af[4], bfv[4];
#pragma unroll
    for (int mt = 0; mt < 4; ++mt) af[mt] = ldA(cur, wr * 64 + mt * 16 + l15, l4);
#pragma unroll
    for (int nt = 0; nt < 4; ++nt) bfv[nt] = ldB(cur, wc * 64 + nt * 16 + l15, l4);
    if (t + 2 < NT) stage(nxt2, (t + 2) * 32);
    __builtin_amdgcn_s_barrier();
    __builtin_amdgcn_s_setprio(1);
#pragma unroll
    for (int mt = 0; mt < 4; ++mt)
#pragma unroll
      for (int nt = 0; nt < 4; ++nt)
        acc[mt][nt] = __builtin_amdgcn_mfma_f32_16x16x32_bf16(af[mt], bfv[nt], acc[mt][nt], 0, 0, 0);
    __builtin_amdgcn_s_setprio(0);
    if (t < NT - 1) {
      if (t + 2 < NT) asm volatile("s_waitcnt vmcnt(4)" ::: "memory");   // counted: t+2 stays in flight
      else            asm volatile("s_waitcnt vmcnt(0)" ::: "memory");   // tail drain
      __builtin_amdgcn_s_barrier();
    }
    cur = (cur < 2) ? cur + 1 : 0;
  }

  const int orow = rowbase + wr * 64, ocol = colbase + wc * 64;
  if (colbase < 2048) {
    // ---- Q: rope + QSCALE -> Qb[row][h*64+d] ----
#pragma unroll
    for (int mt = 0; mt < 4; ++mt)
#pragma unroll
      for (int r = 0; r < 4; ++r) {
        const int row = orow + mt * 16 + l4 * 4 + r;
        const int s = row & 2047;
        const float* cR = cosg + s * 32;
        const float* sR = sing + s * 32;
#pragma unroll
        for (int nt = 0; nt < 2; ++nt) {
          const int i2 = nt * 8 + (l15 >> 1);
          float c0 = cR[i2], sv0 = sR[i2], c1 = cR[16 + i2], sv1 = sR[16 + i2];
          float alo = acc[mt][nt][r], ahi = acc[mt][nt + 2][r];
          size_t base = (size_t)row * 2048 + ocol + nt * 16 + l15;
          Qb[base]      = f2b((alo * c0 - ahi * sv0) * QSCALE);
          Qb[base + 32] = f2b((ahi * c1 + alo * sv1) * QSCALE);
        }
      }
  } else if (colbase < 2560) {
    // ---- K: rope -> Kb2[row][hk*64+d] ----
    const int kcol = ocol - 2048;
#pragma unroll
    for (int mt = 0; mt < 4; ++mt)
#pragma unroll
      for (int r = 0; r < 4; ++r) {
        const int row = orow + mt * 16 + l4 * 4 + r;
        const int s = row & 2047;
        const float* cR = cosg + s * 32;
        const float* sR = sing + s * 32;
#pragma unroll
        for (int nt = 0; nt < 2; ++nt) {
          const int i2 = nt * 8 + (l15 >> 1);
          float c0 = cR[i2], sv0 = sR[i2], c1 = cR[16 + i2], sv1 = sR[16 + i2];
          float alo = acc[mt][nt][r], ahi = acc[mt][nt + 2][r];
          size_t base = (size_t)row * 512 + kcol + nt * 16 + l15;
          Kb2[base]      = f2b(alo * c0 - ahi * sv0);
          Kb2[base + 32] = f2b(ahi * c1 + alo * sv1);
        }
      }
  } else {
    // ---- V: transpose -> Vtb[b,hk,d][s] ----
    const int hkv = (ocol - 2560) >> 6;
#pragma unroll
    for (int mt = 0; mt < 4; ++mt)
#pragma unroll
      for (int nt = 0; nt < 4; ++nt) {
        const int d = nt * 16 + l15;
        const int row0 = orow + mt * 16 + l4 * 4;
        const int b = row0 >> 11, s0i = row0 & 2047;
        ushort4 u;
        u.x = f2b(acc[mt][nt][0]); u.y = f2b(acc[mt][nt][1]);
        u.z = f2b(acc[mt][nt][2]); u.w = f2b(acc[mt][nt][3]);
        *(ushort4*)(Vtb + ((size_t)(b * NKV + hkv) * HD + d) * S_ + s0i) = u;
      }
  }
}

// ---------------- GEMM C[M,N] = A[M,K] * B[N,K]^T  (bf16 in, fp32 out) ----------------
// 256x128 tile, BK=64, triple-buffered, counted vmcnt — grid 256 = 1/CU exact (proven fast).
#define BMg 256
#define BNg 128
#define BKg 64
__global__ __launch_bounds__(512, 2) void gemm_bt(const unsigned short* __restrict__ A,
                                                  const unsigned short* __restrict__ Bm,
                                                  float* __restrict__ C,
                                                  int M, int N, int K) {
  __shared__ unsigned short Abuf[3][BMg * BKg];
  __shared__ unsigned short Bbuf[3][BNg * BKg];
  const int tid = threadIdx.x;
  const int wave = tid >> 6, lane = tid & 63;
  const int wr = wave >> 1, wc = wave & 1;
  const int rowbase = blockIdx.y * BMg;
  const int colbase = blockIdx.x * BNg;
  const unsigned short* Ag = A + (size_t)rowbase * K;
  const unsigned short* Bg = Bm + (size_t)colbase * K;
  const int NT = K / BKg;

  auto stage_half = [&](int buf, int k0, int half) {
#pragma unroll
    for (int i = 0; i < 2; ++i) {
      int c = wave * 256 + (half * 2 + i) * 64 + lane;
      int r = c >> 3, p = c & 7;
      gload16(Ag + (size_t)r * K + k0 + ((p ^ (r & 7)) << 3),
              &Abuf[buf][(wave * 256 + (half * 2 + i) * 64) * 8]);
    }
    int c = wave * 128 + half * 64 + lane;
    int r = c >> 3, p = c & 7;
    gload16(Bg + (size_t)r * K + k0 + ((p ^ (r & 7)) << 3),
            &Bbuf[buf][(wave * 128 + half * 64) * 8]);
  };
  auto ldA = [&](int buf, int row, int c16) -> bf16x8 {
    return *(const bf16x8*)((const char*)&Abuf[buf][0] + row * 128 + ((c16 ^ (row & 7)) << 4));
  };
  auto ldB = [&](int buf, int row, int c16) -> bf16x8 {
    return *(const bf16x8*)((const char*)&Bbuf[buf][0] + row * 128 + ((c16 ^ (row & 7)) << 4));
  };

  f32x4 acc[4][4];
#pragma unroll
  for (int a = 0; a < 4; a++)
#pragma unroll
    for (int b2 = 0; b2 < 4; b2++) acc[a][b2] = (f32x4){0.f, 0.f, 0.f, 0.f};

  const int l15 = lane & 15, l4 = lane >> 4;

  stage_half(0, 0, 0); stage_half(0, 0, 1);
  stage_half(1, BKg, 0); stage_half(1, BKg, 1);
  asm volatile("s_waitcnt vmcnt(6)" ::: "memory");
  __builtin_amdgcn_s_barrier();

  int cur = 0;
  for (int t = 0; t < NT; ++t) {
    const int nxt2 = (cur >= 1) ? cur - 1 : cur + 2;
    {
      bf16x8 af[4], bfv[4];
#pragma unroll
      for (int mt = 0; mt < 4; ++mt) af[mt] = ldA(cur, wr * 64 + mt * 16 + l15, l4);
#pragma unroll
      for (int nt = 0; nt < 4; ++nt) bfv[nt] = ldB(cur, wc * 64 + nt * 16 + l15, l4);
      if (t + 2 < NT) stage_half(nxt2, (t + 2) * BKg, 0);
      __builtin_amdgcn_s_barrier();
      __builtin_amdgcn_s_setprio(1);
#pragma unroll
      for (int mt = 0; mt < 4; ++mt)
#pragma unroll
        for (int nt = 0; nt < 4; ++nt)
          acc[mt][nt] = __builtin_amdgcn_mfma_f32_16x16x32_bf16(af[mt], bfv[nt], acc[mt][nt], 0, 0, 0);
      __builtin_amdgcn_s_setprio(0);
      __builtin_amdgcn_s_barrier();
    }
    {
      bf16x8 af[4], bfv[4];
#pragma unroll
      for (int mt = 0; mt < 4; ++mt) af[mt] = ldA(cur, wr * 64 + mt * 16 + l15, 4 + l4);
#pragma unroll
      for (int nt = 0; nt < 4; ++nt) bfv[nt] = ldB(cur, wc * 64 + nt * 16 + l15, 4 + l4);
      if (t + 2 < NT) stage_half(nxt2, (t + 2) * BKg, 1);
      __builtin_amdgcn_s_barrier();
      __builtin_amdgcn_s_setprio(1);
#pragma unroll
      for (int mt = 0; mt < 4; ++mt)
#pragma unroll
        for (int nt = 0; nt < 4; ++nt)
          acc[mt][nt] = __builtin_amdgcn_mfma_f32_16x16x32_bf16(af[mt], bfv[nt], acc[mt][nt], 0, 0, 0);
      __builtin_amdgcn_s_setprio(0);
      if (t < NT - 1) {
        if (t + 2 < NT) asm volatile("s_waitcnt vmcnt(6)" ::: "memory");
        else            asm volatile("s_waitcnt vmcnt(0)" ::: "memory");
        __builtin_amdgcn_s_barrier();
      }
    }
    cur = (cur < 2) ? cur + 1 : 0;
  }

  const int orow = rowbase + wr * 64, ocol = colbase + wc * 64;
#pragma unroll
  for (int mt = 0; mt < 4; mt++)
#pragma unroll
    for (int nt = 0; nt < 4; nt++)
#pragma unroll
      for (int r = 0; r < 4; r++)
        C[(size_t)(orow + mt * 16 + l4 * 4 + r) * N + ocol + nt * 16 + l15] = acc[mt][nt][r];
}

// ---------------- Flash attention: paired q-regions, KVBLK=128, 17 rounds uniform ----------------
__global__ __launch_bounds__(256, 2) void attn_kernel(const unsigned short* __restrict__ Qb,
                                                      const unsigned short* __restrict__ Kb2,
                                                      const unsigned short* __restrict__ Vt,
                                                      unsigned short* __restrict__ AO) {
  // block pr: region A qbi=15-pr (16-pr rounds of 128 kv), region B qbi=pr (pr+1 rounds) = 17 uniform.
  const int pr = blockIdx.x, h = blockIdx.y, b = blockIdx.z;
  const int hk = h >> 2;
  __shared__ unsigned short Kbuf[2][8192];   // 2 x 16KB: [128 kv][64 d]
  __shared__ unsigned short Vbuf[2][8192];   // 2 x 16KB: [64 d][128 kv]
  const int tid = threadIdx.x, wave = tid >> 6, lane = tid & 63;
  const int l31 = lane & 31, hi = lane >> 5;

  const unsigned short* Qrow = Qb + (size_t)b * S_ * 2048 + h * 64;
  const unsigned short* Krow = Kb2 + (size_t)b * S_ * 512 + hk * 64;
  const unsigned short* Vbase = Vt + (size_t)(b * NKV + hk) * HD * S_;

  const int NT_A = 16 - pr;
  const int NTtot = 17;

  auto j0_of = [&](int tl) { return (tl < NT_A ? tl : tl - NT_A) * 128; };
  auto stage = [&](int j0, int bufi) {
#pragma unroll
    for (int it = 0; it < 4; ++it) {           // K: 128 rows x 8 chunks
      int slot = (wave * 4 + it) * 64 + lane;
      int row = slot >> 3, p = slot & 7;
      gload16(Krow + (size_t)(j0 + row) * 512 + ((p ^ (row & 7)) << 3),
              &Kbuf[bufi][(wave * 4 + it) * 512]);
    }
#pragma unroll
    for (int it = 0; it < 4; ++it) {           // V^T: 64 rows x 16 chunks
      int slot = (wave * 4 + it) * 64 + lane;
      int row = slot >> 4, p = slot & 15;
      gload16(Vbase + (size_t)row * S_ + j0 + ((p ^ (row & 15)) << 3),
              &Vbuf[bufi][(wave * 4 + it) * 512]);
    }
  };

  stage(j0_of(0), 0);
  stage(j0_of(1), 1);
  asm volatile("s_waitcnt vmcnt(8)" ::: "memory");
  __builtin_amdgcn_s_barrier();

  int cur = 0, tlin = 0;

  for (int rg = 0; rg < 2; ++rg) {
    const int qbi = rg == 0 ? (15 - pr) : pr;
    const int qb = qbi * 128;
    const int NT = qbi + 1;
    const int q0w = qb + wave * 32;
    const int qg = q0w + l31;

    bf16x8 qf[4];
#pragma unroll
    for (int c = 0; c < 4; ++c)
      qf[c] = *reinterpret_cast<const bf16x8*>(Qrow + (size_t)qg * 2048 + c * 16 + hi * 8);

    f32x16 Oa0 = {}, Oa1 = {};
    float m_old = -INFINITY, lsum = 0.f;

    for (int t = 0; t < NT; ++t, ++tlin) {
      const int j0 = t * 128;

      if (j0 < q0w + 32) {
        const char* Klc = (const char*)&Kbuf[cur][0];
        const char* Vlc = (const char*)&Vbuf[cur][0];

        // S = K * Q: 4 kv-blocks of 32 (s0..s3), lane owns q = qg
        f32x16 s0 = {}, s1 = {}, s2 = {}, s3 = {};
        __builtin_amdgcn_s_setprio(1);
#pragma unroll
        for (int c = 0; c < 4; ++c) {
          const int xb = ((c << 1) + hi) ^ (l31 & 7);     // (32k+l31)&7 == l31&7
          bf16x8 kf0 = *(const bf16x8*)(Klc + (l31) * 128       + (xb << 4));
          s0 = __builtin_amdgcn_mfma_f32_32x32x16_bf16(kf0, qf[c], s0, 0, 0, 0);
          bf16x8 kf1 = *(const bf16x8*)(Klc + (32 + l31) * 128  + (xb << 4));
          s1 = __builtin_amdgcn_mfma_f32_32x32x16_bf16(kf1, qf[c], s1, 0, 0, 0);
          bf16x8 kf2 = *(const bf16x8*)(Klc + (64 + l31) * 128  + (xb << 4));
          s2 = __builtin_amdgcn_mfma_f32_32x32x16_bf16(kf2, qf[c], s2, 0, 0, 0);
          bf16x8 kf3 = *(const bf16x8*)(Klc + (96 + l31) * 128  + (xb << 4));
          s3 = __builtin_amdgcn_mfma_f32_32x32x16_bf16(kf3, qf[c], s3, 0, 0, 0);
        }
        __builtin_amdgcn_s_setprio(0);

        // causal mask (diagonal rounds only)
        if (j0 + 127 > q0w) {
          const int kb0 = j0 + 4 * hi, kb1 = kb0 + 32, kb2m = kb0 + 64, kb3 = kb0 + 96;
#pragma unroll
          for (int r = 0; r < 16; ++r) {
            const int ko = (r & 3) + 8 * (r >> 2);
            if (kb0 + ko > qg) s0[r] = -INFINITY;
            if (kb1 + ko > qg) s1[r] = -INFINITY;
            if (kb2m + ko > qg) s2[r] = -INFINITY;
            if (kb3 + ko > qg) s3[r] = -INFINITY;
          }
        }

        // row-max: 4 parallel chains over 64 values
        float a0 = fmaxf(fmaxf(s0[0], s1[0]), fmaxf(s2[0], s3[0]));
        float a1 = fmaxf(fmaxf(s0[1], s1[1]), fmaxf(s2[1], s3[1]));
        float a2 = fmaxf(fmaxf(s0[2], s1[2]), fmaxf(s2[2], s3[2]));
        float a3 = fmaxf(fmaxf(s0[3], s1[3]), fmaxf(s2[3], s3[3]));
#pragma unroll
        for (int r = 4; r < 16; r += 4) {
          a0 = fmaxf(a0, fmaxf(fmaxf(s0[r], s1[r]), fmaxf(s2[r], s3[r])));
          a1 = fmaxf(a1, fmaxf(fmaxf(s0[r + 1], s1[r + 1]), fmaxf(s2[r + 1], s3[r + 1])));
          a2 = fmaxf(a2, fmaxf(fmaxf(s0[r + 2], s1[r + 2]), fmaxf(s2[r + 2], s3[r + 2])));
          a3 = fmaxf(a3, fmaxf(fmaxf(s0[r + 3], s1[r + 3]), fmaxf(s2[r + 3], s3[r + 3])));
        }
        float mxt = fmaxf(fmaxf(a0, a1), fmaxf(a2, a3));
        mxt = fmaxf(mxt, __shfl_xor(mxt, 32, 64));

        // defer-rescale (T13)
        if (!__all(mxt - m_old <= 8.f)) {
          float mnew = fmaxf(m_old, mxt);
          float corr = exp2hw(m_old - mnew);
          m_old = mnew;
          lsum *= corr;
#pragma unroll
          for (int r = 0; r < 16; ++r) { Oa0[r] *= corr; Oa1[r] *= corr; }
        }

        // p = 2^(s - m); 4 parallel sum chains
        float t0 = 0.f, t1 = 0.f, t2 = 0.f, t3 = 0.f;
#pragma unroll
        for (int r = 0; r < 16; r += 4) {
          s0[r]     = exp2hw(s0[r] - m_old);     t0 += s0[r];
          s0[r + 1] = exp2hw(s0[r + 1] - m_old); t1 += s0[r + 1];
          s0[r + 2] = exp2hw(s0[r + 2] - m_old); t2 += s0[r + 2];
          s0[r + 3] = exp2hw(s0[r + 3] - m_old); t3 += s0[r + 3];
        }
#pragma unroll
        for (int r = 0; r < 16; r += 4) {
          s1[r]     = exp2hw(s1[r] - m_old);     t0 += s1[r];
          s1[r + 1] = exp2hw(s1[r + 1] - m_old); t1 += s1[r + 1];
          s1[r + 2] = exp2hw(s1[r + 2] - m_old); t2 += s1[r + 2];
          s1[r + 3] = exp2hw(s1[r + 3] - m_old); t3 += s1[r + 3];
        }
#pragma unroll
        for (int r = 0; r < 16; r += 4) {
          s2[r]     = exp2hw(s2[r] - m_old);     t0 += s2[r];
          s2[r + 1] = exp2hw(s2[r + 1] - m_old); t1 += s2[r + 1];
          s2[r + 2] = exp2hw(s2[r + 2] - m_old); t2 += s2[r + 2];
          s2[r + 3] = exp2hw(s2[r + 3] - m_old); t3 += s2[r + 3];
        }
#pragma unroll
        for (int r = 0; r < 16; r += 4) {
          s3[r]     = exp2hw(s3[r] - m_old);     t0 += s3[r];
          s3[r + 1] = exp2hw(s3[r + 1] - m_old); t1 += s3[r + 1];
          s3[r + 2] = exp2hw(s3[r + 2] - m_old); t2 += s3[r + 2];
          s3[r + 3] = exp2hw(s3[r + 3] - m_old); t3 += s3[r + 3];
        }
        float rs = (t0 + t1) + (t2 + t3);
        rs += __shfl_xor(rs, 32, 64);
        lsum += rs;

        // P -> bf16 B-fragments in-register (2 per kv-block)
        bf16x8 pf0, pf1, pf2, pf3, pf4, pf5, pf6, pf7;
        {
          unsigned aA = cvtpk(s0[0], s0[1]),  bA = cvtpk(s0[4], s0[5]);  pl32swap(aA, bA);
          unsigned aB = cvtpk(s0[2], s0[3]),  bB = cvtpk(s0[6], s0[7]);  pl32swap(aB, bB);
          pf0 = mk8(aA, aB, bA, bB);
          unsigned aC = cvtpk(s0[8], s0[9]),  bC = cvtpk(s0[12], s0[13]); pl32swap(aC, bC);
          unsigned aD = cvtpk(s0[10], s0[11]), bD = cvtpk(s0[14], s0[15]); pl32swap(aD, bD);
          pf1 = mk8(aC, aD, bC, bD);
        }
        {
          unsigned aA = cvtpk(s1[0], s1[1]),  bA = cvtpk(s1[4], s1[5]);  pl32swap(aA, bA);
          unsigned aB = cvtpk(s1[2], s1[3]),  bB = cvtpk(s1[6], s1[7]);  pl32swap(aB, bB);
          pf2 = mk8(aA, aB, bA, bB);
          unsigned aC = cvtpk(s1[8], s1[9]),  bC = cvtpk(s1[12], s1[13]); pl32swap(aC, bC);
          unsigned aD = cvtpk(s1[10], s1[11]), bD = cvtpk(s1[14], s1[15]); pl32swap(aD, bD);
          pf3 = mk8(aC, aD, bC, bD);
        }
        {
          unsigned aA = cvtpk(s2[0], s2[1]),  bA = cvtpk(s2[4], s2[5]);  pl32swap(aA, bA);
          unsigned aB = cvtpk(s2[2], s2[3]),  bB = cvtpk(s2[6], s2[7]);  pl32swap(aB, bB);
          pf4 = mk8(aA, aB, bA, bB);
          unsigned aC = cvtpk(s2[8], s2[9]),  bC = cvtpk(s2[12], s2[13]); pl32swap(aC, bC);
          unsigned aD = cvtpk(s2[10], s2[11]), bD = cvtpk(s2[14], s2[15]); pl32swap(aD, bD);
          pf5 = mk8(aC, aD, bC, bD);
        }
        {
          unsigned aA = cvtpk(s3[0], s3[1]),  bA = cvtpk(s3[4], s3[5]);  pl32swap(aA, bA);
          unsigned aB = cvtpk(s3[2], s3[3]),  bB = cvtpk(s3[6], s3[7]);  pl32swap(aB, bB);
          pf6 = mk8(aA, aB, bA, bB);
          unsigned aC = cvtpk(s3[8], s3[9]),  bC = cvtpk(s3[12], s3[13]); pl32swap(aC, bC);
          unsigned aD = cvtpk(s3[10], s3[11]), bD = cvtpk(s3[14], s3[15]); pl32swap(aD, bD);
          pf7 = mk8(aC, aD, bC, bD);
        }

        // O^T += V^T * P  (V rows = d; chunk = sk*2 + hi of 16)
        const int xv = l31 & 15;                 // (32+l31)&15 == l31&15
        __builtin_amdgcn_s_setprio(1);
#define PVSTEP(PF, SK)                                                                     \
        {                                                                                  \
          const int xc = (((SK) << 1) + hi) ^ xv;                                          \
          bf16x8 vf0 = *(const bf16x8*)(Vlc + l31 * 256 + (xc << 4));                      \
          Oa0 = __builtin_amdgcn_mfma_f32_32x32x16_bf16(vf0, PF, Oa0, 0, 0, 0);            \
          bf16x8 vf1 = *(const bf16x8*)(Vlc + (32 + l31) * 256 + (xc << 4));               \
          Oa1 = __builtin_amdgcn_mfma_f32_32x32x16_bf16(vf1, PF, Oa1, 0, 0, 0);            \
        }
        PVSTEP(pf0, 0) PVSTEP(pf1, 1) PVSTEP(pf2, 2) PVSTEP(pf3, 3)
        PVSTEP(pf4, 4) PVSTEP(pf5, 5) PVSTEP(pf6, 6) PVSTEP(pf7, 7)
#undef PVSTEP
        __builtin_amdgcn_s_setprio(0);
      }

      // barrier 1: all waves done reading buf[cur]; then re-stage it with tile t+2
      __builtin_amdgcn_s_barrier();
      if (tlin + 2 < NTtot) stage(j0_of(tlin + 2), cur);
      if (tlin + 1 < NTtot) {
        if (tlin + 2 < NTtot) asm volatile("s_waitcnt vmcnt(8)" ::: "memory");
        else                  asm volatile("s_waitcnt vmcnt(0)" ::: "memory");
        __builtin_amdgcn_s_barrier();          // barrier 2: buf[cur^1] fully staged
      }
      cur ^= 1;
    }

    // epilogue: normalize, direct global stores
    const float inv = 1.0f / lsum;
    unsigned short* ob = AO + (size_t)(b * S_ + qg) * 2048 + h * 64;
#pragma unroll
    for (int c = 0; c < 4; ++c) {
      ushort4 u0, u1;
      u0.x = f2b(Oa0[4 * c] * inv);     u0.y = f2b(Oa0[4 * c + 1] * inv);
      u0.z = f2b(Oa0[4 * c + 2] * inv); u0.w = f2b(Oa0[4 * c + 3] * inv);
      u1.x = f2b(Oa1[4 * c] * inv);     u1.y = f2b(Oa1[4 * c + 1] * inv);
      u1.z = f2b(Oa1[4 * c + 2] * inv); u1.w = f2b(Oa1[4 * c + 3] * inv);
      *(ushort4*)(ob + 8 * c + 4 * hi)      = u0;
      *(ushort4*)(ob + 32 + 8 * c + 4 * hi) = u1;
    }
  }
}

extern "C" void kernel_launch(void* const* d_in, const int* in_sizes, int n_in,
                              void* d_out, int out_size, void* d_ws, size_t ws_size,
                              hipStream_t stream) {
  (void)in_sizes; (void)n_in; (void)out_size; (void)ws_size;
  const float* x    = (const float*)d_in[0];
  const float* wq   = (const float*)d_in[1];
  const float* wk   = (const float*)d_in[2];
  const float* wv   = (const float*)d_in[3];
  const float* wo   = (const float*)d_in[4];
  const float* cosg = (const float*)d_in[5];
  const float* sing = (const float*)d_in[6];

  char* ws = (char*)d_ws;
  unsigned short* xb   = (unsigned short*)(ws);                 // 16,777,216 (reused as AO)
  unsigned short* wcat = (unsigned short*)(ws + 16777216);      // 12,582,912
  unsigned short* wob  = (unsigned short*)(ws + 29360128);      //  8,388,608
  unsigned short* Qb   = (unsigned short*)(ws + 37748736);      // 16,777,216
  unsigned short* Kb2  = (unsigned short*)(ws + 54525952);      //  4,194,304
  unsigned short* Vtb  = (unsigned short*)(ws + 58720256);      //  4,194,304
  unsigned short* AO   = xb;

  f2bf_kernel<<<8192, 256, 0, stream>>>(x, xb, 2097152);
  wcat_kernel<<<6144, 256, 0, stream>>>(wq, wk, wv, wcat);
  f2bf_kernel<<<4096, 256, 0, stream>>>(wo, wob, 1048576);

  gemm_qkv<<<dim3(NQKV / 128, MROWS / 128), 256, 0, stream>>>(xb, wcat, Qb, Kb2, Vtb, cosg, sing);

  attn_kernel<<<dim3(8, NH, B_), 256, 0, stream>>>(Qb, Kb2, Vtb, AO);

  gemm_bt<<<dim3(DM / BNg, MROWS / BMg), 512, 0, stream>>>(AO, wob, (float*)d_out, MROWS, DM, DM);
}